// Round 6
// baseline (601.704 us; speedup 1.0000x reference)
//
#include <hip/hip_runtime.h>
#include <hip/hip_fp16.h>
#include <math.h>
#include <stdint.h>

#define NN 50000
#define NE 800000
#define ET (NE + NN)      // 850000 edges incl self loops
#define FIN 128
#define DD 250
#define HD 256
#define NQ 200000
#define NEG_SLOPE 0.2f

typedef unsigned short u16;
typedef __attribute__((ext_vector_type(4))) float f32x4;
typedef _Float16 h2v __attribute__((ext_vector_type(2)));
typedef _Float16 f16x8 __attribute__((ext_vector_type(8)));

union H2U { h2v h; unsigned int u; };

__device__ __forceinline__ u16 f2h(float v) {
    __half h = __float2half(v);
    return *reinterpret_cast<u16*>(&h);
}
// load 4 fp16 (8B) -> float4 (used by query kernel)
__device__ __forceinline__ float4 ld4h(const u16* p) {
    uint2 r = *(const uint2*)p;
    __half2 a = *(__half2*)&r.x;
    __half2 b = *(__half2*)&r.y;
    float2 fa = __half22float2(a), fb = __half22float2(b);
    return make_float4(fa.x, fa.y, fb.x, fb.y);
}
// packed fp16 max -> v_pk_max_f16
__device__ __forceinline__ h2v hmax2v(h2v a, h2v b) {
    return __builtin_elementwise_max(a, b);
}

// ---------------- DPP wave-64 reductions (VALU pipe, no LDS/bpermute) ----------------

#define DPPMOV(v, ctrl, rm) \
    ((unsigned int)__builtin_amdgcn_update_dpp(0, (int)(v), (ctrl), (rm), 0xF, true))

// packed fp16 pair sum across 64 lanes; result via readlane(63)
__device__ __forceinline__ unsigned int h2_wave_sum63(h2v x) {
    H2U u, t; u.h = x;
    t.u = DPPMOV(u.u, 0x111, 0xF); u.h = u.h + t.h;   // row_shr:1
    t.u = DPPMOV(u.u, 0x112, 0xF); u.h = u.h + t.h;   // row_shr:2
    t.u = DPPMOV(u.u, 0x114, 0xF); u.h = u.h + t.h;   // row_shr:4
    t.u = DPPMOV(u.u, 0x118, 0xF); u.h = u.h + t.h;   // row_shr:8
    t.u = DPPMOV(u.u, 0x142, 0xA); u.h = u.h + t.h;   // row_bcast:15 -> rows 1,3
    t.u = DPPMOV(u.u, 0x143, 0xC); u.h = u.h + t.h;   // row_bcast:31 -> rows 2,3
    return (unsigned int)__builtin_amdgcn_readlane((int)u.u, 63);
}

// fp32 sum across 64 lanes, result uniform (readlane 63)
__device__ __forceinline__ float f32_wave_sum63(float x) {
    union FU { float f; unsigned int u; } a, t, o;
    a.f = x;
    t.u = DPPMOV(a.u, 0x111, 0xF); a.f += t.f;
    t.u = DPPMOV(a.u, 0x112, 0xF); a.f += t.f;
    t.u = DPPMOV(a.u, 0x114, 0xF); a.f += t.f;
    t.u = DPPMOV(a.u, 0x118, 0xF); a.f += t.f;
    t.u = DPPMOV(a.u, 0x142, 0xA); a.f += t.f;
    t.u = DPPMOV(a.u, 0x143, 0xC); a.f += t.f;
    o.u = (unsigned int)__builtin_amdgcn_readlane((int)a.u, 63);
    return o.f;
}

// ---------------- CSR build (parallel 3-dispatch scan) ----------------

__global__ __launch_bounds__(256) void scan1_kernel(
    int* __restrict__ cnt, int* __restrict__ rowptr, int* __restrict__ bsum)
{
    __shared__ int buf[256];
    int t = threadIdx.x;
    int i = blockIdx.x * 256 + t;
    int v = (i < NN) ? cnt[i] : 0;
    if (i < NN) cnt[i] = 0;          // zero fill for scatter
    buf[t] = v;
    __syncthreads();
#pragma unroll
    for (int off = 1; off < 256; off <<= 1) {
        int add = (t >= off) ? buf[t - off] : 0;
        __syncthreads();
        buf[t] += add;
        __syncthreads();
    }
    if (i < NN) rowptr[i] = buf[t] - v;     // block-local exclusive
    if (t == 255) bsum[blockIdx.x] = buf[255];
}

__global__ __launch_bounds__(256) void scan2_kernel(
    int* __restrict__ bsum, int* __restrict__ rowptr, int nb)
{
    __shared__ int buf[256];
    int t = threadIdx.x;
    int v = (t < nb) ? bsum[t] : 0;
    buf[t] = v;
    __syncthreads();
#pragma unroll
    for (int off = 1; off < 256; off <<= 1) {
        int add = (t >= off) ? buf[t - off] : 0;
        __syncthreads();
        buf[t] += add;
        __syncthreads();
    }
    if (t < nb) bsum[t] = buf[t] - v;
    if (t == 255) rowptr[NN] = buf[255];
}

__global__ __launch_bounds__(256) void scan3_kernel(
    int* __restrict__ rowptr, const int* __restrict__ bsum)
{
    int i = blockIdx.x * 256 + threadIdx.x;
    if (i < NN) rowptr[i] += bsum[blockIdx.x];
}

// stores premultiplied src BYTE offset (s*512, fp16-row stride) for the fused kernel
__global__ void scatter_kernel(const int* __restrict__ ei,
                               const int* __restrict__ rowptr,
                               int* __restrict__ fill,
                               int* __restrict__ ssrc) {
    int k = blockIdx.x * 256 + threadIdx.x;
    if (k >= ET) return;
    int s, d;
    if (k < NE) { s = ei[k]; d = ei[NE + k]; }
    else        { s = k - NE; d = k - NE; }
    int pos = rowptr[d] + atomicAdd(&fill[d], 1);
    ssrc[pos] = s << 9;
}

// ---------------- combined conversion + degree-count kernel ----------------

#define CONVX_BLOCKS 3125

__global__ __launch_bounds__(256) void conv_all(
    const float* __restrict__ x, const int* __restrict__ ei,
    u16* __restrict__ Asp,
    const float* __restrict__ W1l, const float* __restrict__ W1r,
    const float* __restrict__ W2l, const float* __restrict__ W2r,
    const float* __restrict__ Wm1,
    const float* __restrict__ att1, const float* __restrict__ att2,
    u16* __restrict__ W1lT, u16* __restrict__ W1rT,
    u16* __restrict__ W2lT, u16* __restrict__ W2rT,
    u16* __restrict__ WmtT, u16* __restrict__ WmbT,
    u16* __restrict__ atth1, u16* __restrict__ atth2,
    int* __restrict__ cnt)
{
    if (blockIdx.x < CONVX_BLOCKS) {
        int tid = blockIdx.x * 256 + threadIdx.x;
        size_t idx = (size_t)tid * 8;
        if (idx >= (size_t)NN * FIN) return;
        float4 v0 = *(const float4*)(x + idx);
        float4 v1 = *(const float4*)(x + idx + 4);
        ushort4 o0, o1;
        o0.x = f2h(v0.x); o0.y = f2h(v0.y); o0.z = f2h(v0.z); o0.w = f2h(v0.w);
        o1.x = f2h(v1.x); o1.y = f2h(v1.y); o1.z = f2h(v1.z); o1.w = f2h(v1.w);
        *(ushort4*)(Asp + idx) = o0;
        *(ushort4*)(Asp + idx + 4) = o1;
        return;
    }
    int b = blockIdx.x - CONVX_BLOCKS;
    if (b < 1280) {
        const float* W; int K, N, koff, kshift, b0; u16* ot;
        if (b < 128)       { W = W1l; K = FIN; N = DD; koff = 0;  kshift = 7; b0 = 0;    ot = W1lT; }
        else if (b < 256)  { W = W1r; K = FIN; N = DD; koff = 0;  kshift = 7; b0 = 128;  ot = W1rT; }
        else if (b < 512)  { W = W2l; K = DD;  N = DD; koff = 0;  kshift = 8; b0 = 256;  ot = W2lT; }
        else if (b < 768)  { W = W2r; K = DD;  N = DD; koff = 0;  kshift = 8; b0 = 512;  ot = W2rT; }
        else if (b < 1024) { W = Wm1; K = DD;  N = HD; koff = 0;  kshift = 8; b0 = 768;  ot = WmtT; }
        else               { W = Wm1; K = DD;  N = HD; koff = DD; kshift = 8; b0 = 1024; ot = WmbT; }
        int id = (b - b0) * 256 + threadIdx.x;
        int Kp = 1 << kshift;
        int n = id >> kshift, k = id & (Kp - 1);
        float v = (n < N && k < K) ? W[(size_t)(k + koff) * N + n] : 0.f;
        ot[id] = f2h(v);
        return;
    }
    if (b < 1282) {
        const float* a = (b == 1280) ? att1 : att2;
        u16* o = (b == 1280) ? atth1 : atth2;
        int id = threadIdx.x;
        o[id] = f2h(id < DD ? a[id] : 0.f);
        return;
    }
    // degree count
    int k = (b - 1282) * 256 + threadIdx.x;
    if (k >= ET) return;
    int d = (k < NE) ? ei[NE + k] : (k - NE);
    atomicAdd(&cnt[d], 1);
}

// ---------------- fp16 MFMA pair-GEMM v4 ----------------
// 128x128 tile, 256 threads (4 waves, 2x2 of 64x64) — per-wave structure and
// swizzle identical to v3, but blocks halved: grid (rows, 2 N-halves) = 782
// blocks. Registers (~212/lane incl AGPR acc) allowed only 8 waves/CU, so v3's
// 512-thread block meant ONE resident block/CU -> 391 blocks = 2 rounds, round
// 2 only 53% occupied (76% util). v4: 2 independent blocks/CU (LDS 48KB), 782
// fine blocks -> ~95% util + cross-block overlap instead of barrier lockstep.
// fmt bit0/1: C0/C1 as fp16 stride-256; else fp32 stride-N

__global__ __launch_bounds__(256) void gemm_pair(
    const u16* __restrict__ A, int Kp,
    const u16* __restrict__ B0, const u16* __restrict__ B1,
    const float* __restrict__ bias0, const float* __restrict__ bias1,
    void* __restrict__ C0v, void* __restrict__ C1v, int M, int N, int fmt)
{
    __shared__ u16 AS[2][128][32], B0S[2][128][32], B1S[2][128][32];  // 48 KB

    int row0 = blockIdx.x * 128;
    int col0 = blockIdx.y * 128;
    int t = threadIdx.x;
    int lane = t & 63, w = t >> 6;
    int wr = w >> 1, wc = w & 1;            // 2 x 2 wave grid -> 64x64 per wave
    int quad = lane >> 4, rr = lane & 15;
    int rcol = (quad ^ ((rr >> 1) & 3)) * 8;   // swizzled read column (u16)

    f32x4 acc0[4][4], acc1[4][4];
#pragma unroll
    for (int i = 0; i < 4; i++)
#pragma unroll
        for (int j = 0; j < 4; j++) {
            acc0[i][j] = (f32x4){0.f, 0.f, 0.f, 0.f};
            acc1[i][j] = (f32x4){0.f, 0.f, 0.f, 0.f};
        }

    // staging: each array has 128 rows x 4 granules = 512 chunks; 256 threads
    // stage chunks t (rows 0..63) and t+256 (rows 64..127), same granule.
    int r1 = t >> 2, g1 = t & 3;
    int r2 = r1 + 64;
    int sc1 = (g1 ^ ((r1 >> 1) & 3)) * 8;   // swizzled write columns
    int sc2 = (g1 ^ ((r2 >> 1) & 3)) * 8;
    bool aok1 = (row0 + r1) < M, aok2 = (row0 + r2) < M;
    const u16* pA1  = A  + (size_t)(row0 + r1) * Kp + g1 * 8;
    const u16* pA2  = A  + (size_t)(row0 + r2) * Kp + g1 * 8;
    const u16* pB01 = B0 + (size_t)(col0 + r1) * Kp + g1 * 8;
    const u16* pB02 = B0 + (size_t)(col0 + r2) * Kp + g1 * 8;
    const u16* pB11 = B1 + (size_t)(col0 + r1) * Kp + g1 * 8;
    const u16* pB12 = B1 + (size_t)(col0 + r2) * Kp + g1 * 8;

    // prologue: stage k0=0 into buffer 0
    {
        f16x8 ra1{}, ra2{};
        if (aok1) ra1 = *(const f16x8*)pA1;
        if (aok2) ra2 = *(const f16x8*)pA2;
        f16x8 rb01 = *(const f16x8*)pB01;
        f16x8 rb02 = *(const f16x8*)pB02;
        f16x8 rb11 = *(const f16x8*)pB11;
        f16x8 rb12 = *(const f16x8*)pB12;
        *(f16x8*)&AS[0][r1][sc1]  = ra1;
        *(f16x8*)&AS[0][r2][sc2]  = ra2;
        *(f16x8*)&B0S[0][r1][sc1] = rb01;
        *(f16x8*)&B0S[0][r2][sc2] = rb02;
        *(f16x8*)&B1S[0][r1][sc1] = rb11;
        *(f16x8*)&B1S[0][r2][sc2] = rb12;
    }
    __syncthreads();

    int cur = 0;
    for (int k0 = 0; k0 < Kp; k0 += 32) {
        int kn = k0 + 32;
        bool more = kn < Kp;
        // issue next K-step's global loads EARLY (latency hides under MFMA phase)
        f16x8 ra1{}, ra2{}, rb01{}, rb02{}, rb11{}, rb12{};
        if (more) {
            if (aok1) ra1 = *(const f16x8*)(pA1 + kn);
            if (aok2) ra2 = *(const f16x8*)(pA2 + kn);
            rb01 = *(const f16x8*)(pB01 + kn);
            rb02 = *(const f16x8*)(pB02 + kn);
            rb11 = *(const f16x8*)(pB11 + kn);
            rb12 = *(const f16x8*)(pB12 + kn);
        }

        // ---- compute current buffer ----
        f16x8 fA[4];
#pragma unroll
        for (int fi = 0; fi < 4; fi++) {
            int r = wr * 64 + fi * 16 + rr;
            fA[fi] = *(const f16x8*)&AS[cur][r][rcol];
        }
#pragma unroll
        for (int fj = 0; fj < 4; fj++) {
            int c = wc * 64 + fj * 16 + rr;
            f16x8 b0 = *(const f16x8*)&B0S[cur][c][rcol];
            f16x8 b1 = *(const f16x8*)&B1S[cur][c][rcol];
#pragma unroll
            for (int fi = 0; fi < 4; fi++) {
                acc0[fi][fj] = __builtin_amdgcn_mfma_f32_16x16x32_f16(fA[fi], b0, acc0[fi][fj], 0, 0, 0);
                acc1[fi][fj] = __builtin_amdgcn_mfma_f32_16x16x32_f16(fA[fi], b1, acc1[fi][fj], 0, 0, 0);
            }
        }

        // write next buffer late; one barrier per K-step
        if (more) {
            int nb_ = cur ^ 1;
            *(f16x8*)&AS[nb_][r1][sc1]  = ra1;
            *(f16x8*)&AS[nb_][r2][sc2]  = ra2;
            *(f16x8*)&B0S[nb_][r1][sc1] = rb01;
            *(f16x8*)&B0S[nb_][r2][sc2] = rb02;
            *(f16x8*)&B1S[nb_][r1][sc1] = rb11;
            *(f16x8*)&B1S[nb_][r2][sc2] = rb12;
            __syncthreads();
            cur = nb_;
        }
    }

#pragma unroll
    for (int fj = 0; fj < 4; fj++) {
        int gc = col0 + wc * 64 + fj * 16 + rr;
        if (gc >= N) continue;
        float bb0 = bias0 ? bias0[gc] : 0.f;
        float bb1 = bias1 ? bias1[gc] : 0.f;
#pragma unroll
        for (int fi = 0; fi < 4; fi++) {
#pragma unroll
            for (int r = 0; r < 4; r++) {
                int grr = row0 + wr * 64 + fi * 16 + quad * 4 + r;
                if (grr < M) {
                    float v0 = acc0[fi][fj][r] + bb0;
                    float v1 = acc1[fi][fj][r] + bb1;
                    if (fmt & 1) ((u16*)C0v)[(size_t)grr * 256 + gc] = f2h(v0);
                    else         ((float*)C0v)[(size_t)grr * N + gc] = v0;
                    if (fmt & 2) ((u16*)C1v)[(size_t)grr * 256 + gc] = f2h(v1);
                    else         ((float*)C1v)[(size_t)grr * N + gc] = v1;
                }
            }
        }
    }
}

// ---------------- fused edge phase: packed-fp16 single-pass softmax+aggregate ----------------
// r4 structure (1 node/wave, 2-deep gather pipeline) — at its measured plateau.

__global__ __launch_bounds__(256) void fused_edge_kernel(
    const int* __restrict__ rowptr, const int* __restrict__ ssrc,
    const u16* __restrict__ xl16, const u16* __restrict__ xr16,
    const u16* __restrict__ atth,
    u16* __restrict__ Oh, int dorelu)
{
    int i = blockIdx.x * 4 + (threadIdx.x >> 6);
    if (i >= NN) return;
    int lane = threadIdx.x & 63;
    int d0 = lane * 4;
    int lb = d0 * 2;                 // lane byte offset into fp16 row

    uint2 atr = *(const uint2*)&atth[d0];
    h2v at0h = *(h2v*)&atr.x, at1h = *(h2v*)&atr.y;
    const h2v c02 = {(_Float16)0.2f, (_Float16)0.2f};
    const char* xlb = (const char*)xl16;

    uint2 xrr = *(const uint2*)&xr16[(size_t)i * 256 + d0];
    h2v xr0h = *(h2v*)&xrr.x, xr1h = *(h2v*)&xrr.y;

    int beg = __builtin_amdgcn_readfirstlane(rowptr[i]);
    int end = __builtin_amdgcn_readfirstlane(rowptr[i + 1]);

    float m = -1e30f, ssum = 0.f;
    float4 acc = make_float4(0.f, 0.f, 0.f, 0.f);

    auto ldrow = [&](int o) -> uint2 {
        return *(const uint2*)(xlb + o + lb);
    };
    auto edge_score = [&](uint2 g) -> float {
        h2v x0 = *(h2v*)&g.x, x1 = *(h2v*)&g.y;
        h2v s = x0 + xr0h; s = hmax2v(s, s * c02);
        float e = __builtin_amdgcn_fdot2(s, at0h, 0.f, false);
        s = x1 + xr1h; s = hmax2v(s, s * c02);
        return __builtin_amdgcn_fdot2(s, at1h, e, false);
    };
    auto single_update = [&](uint2 g) {
        float e = f32_wave_sum63(edge_score(g));
        h2v x0 = *(h2v*)&g.x, x1 = *(h2v*)&g.y;
        float nm = fmaxf(m, e);
        float sc = __expf(m - nm);
        float w = __expf(e - nm);
        acc.x = fmaf(w, (float)x0.x, acc.x * sc);
        acc.y = fmaf(w, (float)x0.y, acc.y * sc);
        acc.z = fmaf(w, (float)x1.x, acc.z * sc);
        acc.w = fmaf(w, (float)x1.y, acc.w * sc);
        ssum = fmaf(ssum, sc, w);
        m = nm;
    };

    int p = beg;
    if (p + 3 < end) {
        // ---- prologue: block A gathers, block B gathers, block C offsets ----
        int o0 = __builtin_amdgcn_readfirstlane(ssrc[p]);
        int o1 = __builtin_amdgcn_readfirstlane(ssrc[p + 1]);
        int o2 = __builtin_amdgcn_readfirstlane(ssrc[p + 2]);
        int o3 = __builtin_amdgcn_readfirstlane(ssrc[p + 3]);
        uint2 a0 = ldrow(o0), a1 = ldrow(o1), a2 = ldrow(o2), a3 = ldrow(o3);

        bool hB = (p + 7 < end);
        uint2 b0, b1, b2, b3;
        if (hB) {
            int q0 = __builtin_amdgcn_readfirstlane(ssrc[p + 4]);
            int q1 = __builtin_amdgcn_readfirstlane(ssrc[p + 5]);
            int q2 = __builtin_amdgcn_readfirstlane(ssrc[p + 6]);
            int q3 = __builtin_amdgcn_readfirstlane(ssrc[p + 7]);
            b0 = ldrow(q0); b1 = ldrow(q1); b2 = ldrow(q2); b3 = ldrow(q3);
        }
        bool hC = (p + 11 < end);
        int co0 = 0, co1 = 0, co2 = 0, co3 = 0;
        if (hC) {
            co0 = __builtin_amdgcn_readfirstlane(ssrc[p + 8]);
            co1 = __builtin_amdgcn_readfirstlane(ssrc[p + 9]);
            co2 = __builtin_amdgcn_readfirstlane(ssrc[p + 10]);
            co3 = __builtin_amdgcn_readfirstlane(ssrc[p + 11]);
        }

        for (;;) {
            // issue block-C gathers (2 blocks ahead of compute)
            uint2 cg0, cg1, cg2, cg3;
            if (hC) {
                cg0 = ldrow(co0); cg1 = ldrow(co1); cg2 = ldrow(co2); cg3 = ldrow(co3);
            }
            // fetch block-D offsets
            bool hD = (p + 15 < end);
            int do0 = 0, do1 = 0, do2 = 0, do3 = 0;
            if (hD) {
                do0 = __builtin_amdgcn_readfirstlane(ssrc[p + 12]);
                do1 = __builtin_amdgcn_readfirstlane(ssrc[p + 13]);
                do2 = __builtin_amdgcn_readfirstlane(ssrc[p + 14]);
                do3 = __builtin_amdgcn_readfirstlane(ssrc[p + 15]);
            }

            // ---- compute block A ----
            h2v x00 = *(h2v*)&a0.x, x01 = *(h2v*)&a0.y;
            h2v x10 = *(h2v*)&a1.x, x11 = *(h2v*)&a1.y;
            h2v x20 = *(h2v*)&a2.x, x21 = *(h2v*)&a2.y;
            h2v x30 = *(h2v*)&a3.x, x31 = *(h2v*)&a3.y;

            h2v s;
            float e0, e1, e2, e3;
            s = x00 + xr0h; s = hmax2v(s, s * c02);
            e0 = __builtin_amdgcn_fdot2(s, at0h, 0.f, false);
            s = x01 + xr1h; s = hmax2v(s, s * c02);
            e0 = __builtin_amdgcn_fdot2(s, at1h, e0, false);
            s = x10 + xr0h; s = hmax2v(s, s * c02);
            e1 = __builtin_amdgcn_fdot2(s, at0h, 0.f, false);
            s = x11 + xr1h; s = hmax2v(s, s * c02);
            e1 = __builtin_amdgcn_fdot2(s, at1h, e1, false);
            s = x20 + xr0h; s = hmax2v(s, s * c02);
            e2 = __builtin_amdgcn_fdot2(s, at0h, 0.f, false);
            s = x21 + xr1h; s = hmax2v(s, s * c02);
            e2 = __builtin_amdgcn_fdot2(s, at1h, e2, false);
            s = x30 + xr0h; s = hmax2v(s, s * c02);
            e3 = __builtin_amdgcn_fdot2(s, at0h, 0.f, false);
            s = x31 + xr1h; s = hmax2v(s, s * c02);
            e3 = __builtin_amdgcn_fdot2(s, at1h, e3, false);

            // packed-pair DPP reduce: two independent VALU chains
            H2U u01, u23, r01, r23;
            u01.h.x = (_Float16)e0; u01.h.y = (_Float16)e1;
            u23.h.x = (_Float16)e2; u23.h.y = (_Float16)e3;
            r01.u = h2_wave_sum63(u01.h);
            r23.u = h2_wave_sum63(u23.h);
            float es0 = (float)r01.h.x, es1 = (float)r01.h.y;
            float es2 = (float)r23.h.x, es3 = (float)r23.h.y;

            float nm = fmaxf(fmaxf(m, es0), fmaxf(fmaxf(es1, es2), es3));
            float sc = __expf(m - nm);
            float w0 = __expf(es0 - nm);
            float w1 = __expf(es1 - nm);
            float w2 = __expf(es2 - nm);
            float w3 = __expf(es3 - nm);
            float ax0 = fmaf(w1, (float)x10.x, w0 * (float)x00.x);
            float ax1 = fmaf(w3, (float)x30.x, w2 * (float)x20.x);
            float ay0 = fmaf(w1, (float)x10.y, w0 * (float)x00.y);
            float ay1 = fmaf(w3, (float)x30.y, w2 * (float)x20.y);
            float az0 = fmaf(w1, (float)x11.x, w0 * (float)x01.x);
            float az1 = fmaf(w3, (float)x31.x, w2 * (float)x21.x);
            float aw0 = fmaf(w1, (float)x11.y, w0 * (float)x01.y);
            float aw1 = fmaf(w3, (float)x31.y, w2 * (float)x21.y);
            acc.x = fmaf(acc.x, sc, ax0 + ax1);
            acc.y = fmaf(acc.y, sc, ay0 + ay1);
            acc.z = fmaf(acc.z, sc, az0 + az1);
            acc.w = fmaf(acc.w, sc, aw0 + aw1);
            ssum = fmaf(ssum, sc, (w0 + w1) + (w2 + w3));
            m = nm;

            p += 4;
            if (!hB) break;
            // rotate pipeline: A <- B <- C; C-offsets <- D-offsets
            a0 = b0; a1 = b1; a2 = b2; a3 = b3;
            b0 = cg0; b1 = cg1; b2 = cg2; b3 = cg3;
            hB = hC; hC = hD;
            co0 = do0; co1 = do1; co2 = do2; co3 = do3;
        }
    }

    // remainder (0..3 edges): hoist gathers ahead of processing
    int rem = end - p;
    if (rem > 0) {
        int o0 = __builtin_amdgcn_readfirstlane(ssrc[p]);
        int o1 = 0, o2 = 0;
        if (rem > 1) o1 = __builtin_amdgcn_readfirstlane(ssrc[p + 1]);
        if (rem > 2) o2 = __builtin_amdgcn_readfirstlane(ssrc[p + 2]);
        uint2 g0 = ldrow(o0);
        uint2 g1, g2;
        if (rem > 1) g1 = ldrow(o1);
        if (rem > 2) g2 = ldrow(o2);
        single_update(g0);
        if (rem > 1) single_update(g1);
        if (rem > 2) single_update(g2);
    }

    float inv = 1.f / ssum;
    acc.x *= inv; acc.y *= inv; acc.z *= inv; acc.w *= inv;
    if (dorelu) {
        acc.x = fmaxf(acc.x, 0.f); acc.y = fmaxf(acc.y, 0.f);
        acc.z = fmaxf(acc.z, 0.f); acc.w = fmaxf(acc.w, 0.f);
    }
    size_t obase = (size_t)i * 256 + d0;
    ushort4 hv;
    hv.x = f2h(acc.x); hv.y = f2h(acc.y); hv.z = f2h(acc.z); hv.w = f2h(acc.w);
    *(ushort4*)&Oh[obase] = hv;   // pad lanes harmless; B k-pads are zero
}

// ---------------- query head: 4 queries per wave; 8 gathers in flight ----------------

__global__ __launch_bounds__(256) void query_kernel(
    const int* __restrict__ qry, const u16* __restrict__ Ptop,
    const u16* __restrict__ Pbot, const float* __restrict__ Wm2,
    const float* __restrict__ bm2, float* __restrict__ out)
{
    int q = (blockIdx.x * 4 + (threadIdx.x >> 6)) * 4;
    if (q >= NQ) return;
    int lane = threadIdx.x & 63;
    int a0 = __builtin_amdgcn_readfirstlane(qry[q * 2 + 0]);
    int b0 = __builtin_amdgcn_readfirstlane(qry[q * 2 + 1]);
    int a1 = __builtin_amdgcn_readfirstlane(qry[q * 2 + 2]);
    int b1 = __builtin_amdgcn_readfirstlane(qry[q * 2 + 3]);
    int a2 = __builtin_amdgcn_readfirstlane(qry[q * 2 + 4]);
    int b2 = __builtin_amdgcn_readfirstlane(qry[q * 2 + 5]);
    int a3 = __builtin_amdgcn_readfirstlane(qry[q * 2 + 6]);
    int b3 = __builtin_amdgcn_readfirstlane(qry[q * 2 + 7]);
    float4 w  = *(const float4*)&Wm2[lane * 4];
    float4 t0 = ld4h(&Ptop[(size_t)a0 * HD + lane * 4]);
    float4 v0 = ld4h(&Pbot[(size_t)b0 * HD + lane * 4]);
    float4 t1 = ld4h(&Ptop[(size_t)a1 * HD + lane * 4]);
    float4 v1 = ld4h(&Pbot[(size_t)b1 * HD + lane * 4]);
    float4 t2 = ld4h(&Ptop[(size_t)a2 * HD + lane * 4]);
    float4 v2 = ld4h(&Pbot[(size_t)b2 * HD + lane * 4]);
    float4 t3 = ld4h(&Ptop[(size_t)a3 * HD + lane * 4]);
    float4 v3 = ld4h(&Pbot[(size_t)b3 * HD + lane * 4]);
    float s0 = fmaxf(t0.x + v0.x, 0.f) * w.x + fmaxf(t0.y + v0.y, 0.f) * w.y
             + fmaxf(t0.z + v0.z, 0.f) * w.z + fmaxf(t0.w + v0.w, 0.f) * w.w;
    float s1 = fmaxf(t1.x + v1.x, 0.f) * w.x + fmaxf(t1.y + v1.y, 0.f) * w.y
             + fmaxf(t1.z + v1.z, 0.f) * w.z + fmaxf(t1.w + v1.w, 0.f) * w.w;
    float s2 = fmaxf(t2.x + v2.x, 0.f) * w.x + fmaxf(t2.y + v2.y, 0.f) * w.y
             + fmaxf(t2.z + v2.z, 0.f) * w.z + fmaxf(t2.w + v2.w, 0.f) * w.w;
    float s3 = fmaxf(t3.x + v3.x, 0.f) * w.x + fmaxf(t3.y + v3.y, 0.f) * w.y
             + fmaxf(t3.z + v3.z, 0.f) * w.z + fmaxf(t3.w + v3.w, 0.f) * w.w;
    s0 = f32_wave_sum63(s0);
    s1 = f32_wave_sum63(s1);
    s2 = f32_wave_sum63(s2);
    s3 = f32_wave_sum63(s3);
    if (lane == 0) {
        float bb = bm2[0];
        out[q]     = fmaxf(s0 + bb, 0.f);
        out[q + 1] = fmaxf(s1 + bb, 0.f);
        out[q + 2] = fmaxf(s2 + bb, 0.f);
        out[q + 3] = fmaxf(s3 + bb, 0.f);
    }
}

// ---------------- launch ----------------

extern "C" void kernel_launch(void* const* d_in, const int* in_sizes, int n_in,
                              void* d_out, int out_size, void* d_ws, size_t ws_size,
                              hipStream_t stream) {
    const float* x    = (const float*)d_in[0];
    const int*   ei   = (const int*)d_in[1];
    const int*   qry  = (const int*)d_in[2];
    const float* W1l  = (const float*)d_in[3];
    const float* b1l  = (const float*)d_in[4];
    const float* W1r  = (const float*)d_in[5];
    const float* b1r  = (const float*)d_in[6];
    const float* att1 = (const float*)d_in[7];
    const float* W2l  = (const float*)d_in[8];
    const float* b2l  = (const float*)d_in[9];
    const float* W2r  = (const float*)d_in[10];
    const float* b2r  = (const float*)d_in[11];
    const float* att2 = (const float*)d_in[12];
    const float* Wm1  = (const float*)d_in[13];
    const float* bm1  = (const float*)d_in[14];
    const float* Wm2  = (const float*)d_in[15];
    const float* bm2  = (const float*)d_in[16];
    float* out = (float*)d_out;

    // workspace carve-up (all node tensors fp16 stride-256)
    u16* xl16    = (u16*)d_ws;                   // NN*256 halfs (25.6 MB)
    u16* xr16    = xl16 + (size_t)NN * 256;      // NN*256 halfs (25.6 MB)
    int* rowptr  = (int*)(xr16 + (size_t)NN * 256);  // NN+1
    int* fill    = rowptr + NN + 1;              // NN (count buffer)
    int* ssrc    = fill + NN;                    // ET
    int* bsum    = ssrc + ET;                    // 256
    u16* atth1   = (u16*)(bsum + 256);           // 256 halfs
    u16* atth2   = atth1 + 256;                  // 256 halfs
    uintptr_t wp = (uintptr_t)(atth2 + 256);
    wp = (wp + 63) & ~(uintptr_t)63;
    u16* W1lT = (u16*)wp;                        // 256*128 each
    u16* W1rT = W1lT + 256 * 128;
    u16* W2lT = W1rT + 256 * 128;                // 256*256 each from here
    u16* W2rT = W2lT + 65536;
    u16* WmtT = W2rT + 65536;
    u16* WmbT = WmtT + 65536;
    u16* Asp  = WmbT + 65536;                    // NN*256 fp16
    u16* Ptop16 = xl16;                          // head overlays (dead after layer-2)
    u16* Pbot16 = xr16;

    dim3 blk(256);
    int gET = (ET + 255) / 256;
    int gNode = (NN + 3) / 4;                    // 4 waves/block, 1 node/wave
    int nb = (NN + 255) / 256;                   // 196 scan blocks
    dim3 gg((NN + 127) / 128, 2);                // 782 gemm blocks (128x128 tiles)

    // ---- zero degree counters (graph-capture-safe), then conversions + count ----
    hipMemsetAsync(fill, 0, (size_t)NN * sizeof(int), stream);
    conv_all<<<CONVX_BLOCKS + 1282 + gET, blk, 0, stream>>>(x, ei, Asp,
        W1l, W1r, W2l, W2r, Wm1, att1, att2,
        W1lT, W1rT, W2lT, W2rT, WmtT, WmbT, atth1, atth2, fill);

    // ---- CSR build (parallel 3-dispatch scan) ----
    scan1_kernel<<<nb, blk, 0, stream>>>(fill, rowptr, bsum);   // also zeroes fill
    scan2_kernel<<<1, blk, 0, stream>>>(bsum, rowptr, nb);
    scan3_kernel<<<nb, blk, 0, stream>>>(rowptr, bsum);
    scatter_kernel<<<gET, blk, 0, stream>>>(ei, rowptr, fill, ssrc);

    // ---- layer 1 (A = x fp16, Kp=128): both outputs fp16 stride-256 ----
    gemm_pair<<<gg, blk, 0, stream>>>(Asp, 128, W1lT, W1rT,
                                      b1l, b1r, (void*)xl16, (void*)xr16, NN, DD, 3);
    fused_edge_kernel<<<gNode, blk, 0, stream>>>(rowptr, ssrc, xl16, xr16, atth1, Asp, 1);

    // ---- layer 2 (A = h fp16, Kp=256) ----
    gemm_pair<<<gg, blk, 0, stream>>>(Asp, 256, W2lT, W2rT,
                                      b2l, b2r, (void*)xl16, (void*)xr16, NN, DD, 3);
    fused_edge_kernel<<<gNode, blk, 0, stream>>>(rowptr, ssrc, xl16, xr16, atth2, Asp, 0);

    // ---- head precompute (A = emb fp16, Kp=256): both outputs fp16 ----
    gemm_pair<<<gg, blk, 0, stream>>>(Asp, 256, WmtT, WmbT,
                                      bm1, (const float*)nullptr, (void*)Ptop16, (void*)Pbot16, NN, HD, 3);

    // ---- per-query head ----
    query_kernel<<<(NQ / 4 + 3) / 4, blk, 0, stream>>>(qry, Ptop16, Pbot16, Wm2, bm2, out);
}

// Round 7
// 455.687 us; speedup vs baseline: 1.3204x; 1.3204x over previous
//
#include <hip/hip_runtime.h>
#include <hip/hip_fp16.h>
#include <math.h>
#include <stdint.h>

#define NN 50000
#define NE 800000
#define ET (NE + NN)      // 850000 edges incl self loops
#define FIN 128
#define DD 250
#define HD 256
#define NQ 200000
#define NEG_SLOPE 0.2f

typedef unsigned short u16;
typedef __attribute__((ext_vector_type(4))) float f32x4;
typedef _Float16 h2v __attribute__((ext_vector_type(2)));
typedef _Float16 f16x8 __attribute__((ext_vector_type(8)));

union H2U { h2v h; unsigned int u; };

__device__ __forceinline__ u16 f2h(float v) {
    __half h = __float2half(v);
    return *reinterpret_cast<u16*>(&h);
}
// load 4 fp16 (8B) -> float4 (used by query kernel)
__device__ __forceinline__ float4 ld4h(const u16* p) {
    uint2 r = *(const uint2*)p;
    __half2 a = *(__half2*)&r.x;
    __half2 b = *(__half2*)&r.y;
    float2 fa = __half22float2(a), fb = __half22float2(b);
    return make_float4(fa.x, fa.y, fb.x, fb.y);
}
// packed fp16 max -> v_pk_max_f16
__device__ __forceinline__ h2v hmax2v(h2v a, h2v b) {
    return __builtin_elementwise_max(a, b);
}

// ---------------- DPP wave-64 reductions (VALU pipe, no LDS/bpermute) ----------------

#define DPPMOV(v, ctrl, rm) \
    ((unsigned int)__builtin_amdgcn_update_dpp(0, (int)(v), (ctrl), (rm), 0xF, true))

// packed fp16 pair sum across 64 lanes; result via readlane(63)
__device__ __forceinline__ unsigned int h2_wave_sum63(h2v x) {
    H2U u, t; u.h = x;
    t.u = DPPMOV(u.u, 0x111, 0xF); u.h = u.h + t.h;   // row_shr:1
    t.u = DPPMOV(u.u, 0x112, 0xF); u.h = u.h + t.h;   // row_shr:2
    t.u = DPPMOV(u.u, 0x114, 0xF); u.h = u.h + t.h;   // row_shr:4
    t.u = DPPMOV(u.u, 0x118, 0xF); u.h = u.h + t.h;   // row_shr:8
    t.u = DPPMOV(u.u, 0x142, 0xA); u.h = u.h + t.h;   // row_bcast:15 -> rows 1,3
    t.u = DPPMOV(u.u, 0x143, 0xC); u.h = u.h + t.h;   // row_bcast:31 -> rows 2,3
    return (unsigned int)__builtin_amdgcn_readlane((int)u.u, 63);
}

// fp32 sum across 64 lanes, result uniform (readlane 63)
__device__ __forceinline__ float f32_wave_sum63(float x) {
    union FU { float f; unsigned int u; } a, t, o;
    a.f = x;
    t.u = DPPMOV(a.u, 0x111, 0xF); a.f += t.f;
    t.u = DPPMOV(a.u, 0x112, 0xF); a.f += t.f;
    t.u = DPPMOV(a.u, 0x114, 0xF); a.f += t.f;
    t.u = DPPMOV(a.u, 0x118, 0xF); a.f += t.f;
    t.u = DPPMOV(a.u, 0x142, 0xA); a.f += t.f;
    t.u = DPPMOV(a.u, 0x143, 0xC); a.f += t.f;
    o.u = (unsigned int)__builtin_amdgcn_readlane((int)a.u, 63);
    return o.f;
}

// ---------------- CSR build (parallel 3-dispatch scan) ----------------

__global__ __launch_bounds__(256) void scan1_kernel(
    int* __restrict__ cnt, int* __restrict__ rowptr, int* __restrict__ bsum)
{
    __shared__ int buf[256];
    int t = threadIdx.x;
    int i = blockIdx.x * 256 + t;
    int v = (i < NN) ? cnt[i] : 0;
    if (i < NN) cnt[i] = 0;          // zero fill for scatter
    buf[t] = v;
    __syncthreads();
#pragma unroll
    for (int off = 1; off < 256; off <<= 1) {
        int add = (t >= off) ? buf[t - off] : 0;
        __syncthreads();
        buf[t] += add;
        __syncthreads();
    }
    if (i < NN) rowptr[i] = buf[t] - v;     // block-local exclusive
    if (t == 255) bsum[blockIdx.x] = buf[255];
}

__global__ __launch_bounds__(256) void scan2_kernel(
    int* __restrict__ bsum, int* __restrict__ rowptr, int nb)
{
    __shared__ int buf[256];
    int t = threadIdx.x;
    int v = (t < nb) ? bsum[t] : 0;
    buf[t] = v;
    __syncthreads();
#pragma unroll
    for (int off = 1; off < 256; off <<= 1) {
        int add = (t >= off) ? buf[t - off] : 0;
        __syncthreads();
        buf[t] += add;
        __syncthreads();
    }
    if (t < nb) bsum[t] = buf[t] - v;
    if (t == 255) rowptr[NN] = buf[255];
}

__global__ __launch_bounds__(256) void scan3_kernel(
    int* __restrict__ rowptr, const int* __restrict__ bsum)
{
    int i = blockIdx.x * 256 + threadIdx.x;
    if (i < NN) rowptr[i] += bsum[blockIdx.x];
}

// stores premultiplied src BYTE offset (s*512, fp16-row stride) for the fused kernel
__global__ void scatter_kernel(const int* __restrict__ ei,
                               const int* __restrict__ rowptr,
                               int* __restrict__ fill,
                               int* __restrict__ ssrc) {
    int k = blockIdx.x * 256 + threadIdx.x;
    if (k >= ET) return;
    int s, d;
    if (k < NE) { s = ei[k]; d = ei[NE + k]; }
    else        { s = k - NE; d = k - NE; }
    int pos = rowptr[d] + atomicAdd(&fill[d], 1);
    ssrc[pos] = s << 9;
}

// ---------------- combined conversion + degree-count kernel ----------------

#define CONVX_BLOCKS 3125

__global__ __launch_bounds__(256) void conv_all(
    const float* __restrict__ x, const int* __restrict__ ei,
    u16* __restrict__ Asp,
    const float* __restrict__ W1l, const float* __restrict__ W1r,
    const float* __restrict__ W2l, const float* __restrict__ W2r,
    const float* __restrict__ Wm1,
    const float* __restrict__ att1, const float* __restrict__ att2,
    u16* __restrict__ W1lT, u16* __restrict__ W1rT,
    u16* __restrict__ W2lT, u16* __restrict__ W2rT,
    u16* __restrict__ WmtT, u16* __restrict__ WmbT,
    u16* __restrict__ atth1, u16* __restrict__ atth2,
    int* __restrict__ cnt)
{
    if (blockIdx.x < CONVX_BLOCKS) {
        int tid = blockIdx.x * 256 + threadIdx.x;
        size_t idx = (size_t)tid * 8;
        if (idx >= (size_t)NN * FIN) return;
        float4 v0 = *(const float4*)(x + idx);
        float4 v1 = *(const float4*)(x + idx + 4);
        ushort4 o0, o1;
        o0.x = f2h(v0.x); o0.y = f2h(v0.y); o0.z = f2h(v0.z); o0.w = f2h(v0.w);
        o1.x = f2h(v1.x); o1.y = f2h(v1.y); o1.z = f2h(v1.z); o1.w = f2h(v1.w);
        *(ushort4*)(Asp + idx) = o0;
        *(ushort4*)(Asp + idx + 4) = o1;
        return;
    }
    int b = blockIdx.x - CONVX_BLOCKS;
    if (b < 1280) {
        const float* W; int K, N, koff, kshift, b0; u16* ot;
        if (b < 128)       { W = W1l; K = FIN; N = DD; koff = 0;  kshift = 7; b0 = 0;    ot = W1lT; }
        else if (b < 256)  { W = W1r; K = FIN; N = DD; koff = 0;  kshift = 7; b0 = 128;  ot = W1rT; }
        else if (b < 512)  { W = W2l; K = DD;  N = DD; koff = 0;  kshift = 8; b0 = 256;  ot = W2lT; }
        else if (b < 768)  { W = W2r; K = DD;  N = DD; koff = 0;  kshift = 8; b0 = 512;  ot = W2rT; }
        else if (b < 1024) { W = Wm1; K = DD;  N = HD; koff = 0;  kshift = 8; b0 = 768;  ot = WmtT; }
        else               { W = Wm1; K = DD;  N = HD; koff = DD; kshift = 8; b0 = 1024; ot = WmbT; }
        int id = (b - b0) * 256 + threadIdx.x;
        int Kp = 1 << kshift;
        int n = id >> kshift, k = id & (Kp - 1);
        float v = (n < N && k < K) ? W[(size_t)(k + koff) * N + n] : 0.f;
        ot[id] = f2h(v);
        return;
    }
    if (b < 1282) {
        const float* a = (b == 1280) ? att1 : att2;
        u16* o = (b == 1280) ? atth1 : atth2;
        int id = threadIdx.x;
        o[id] = f2h(id < DD ? a[id] : 0.f);
        return;
    }
    // degree count
    int k = (b - 1282) * 256 + threadIdx.x;
    if (k >= ET) return;
    int d = (k < NE) ? ei[NE + k] : (k - NE);
    atomicAdd(&cnt[d], 1);
}

// ---------------- fp16 MFMA pair-GEMM v5 ----------------
// 128x128 tile, 512 threads (8 waves, 2x4 of 64x32 per output). Post-mortem of
// v4 (r6): 256-thr/64x64-per-wave doubled acc to 128 regs -> VGPR 168 -> 1
// wave/SIMD -> 97us. v5 halves per-wave acc to 64 regs and stages only 3
// chunks/thread; __launch_bounds__(512,4) pins VGPR<=128 so TWO 8-wave blocks
// co-reside per CU (LDS 2x48KB): fine blocks (782) smooth the tail AND
// cross-block overlap hides the per-K-step barrier. Swizzle identical to
// v3/v4 (measured SQ_LDS_BANK_CONFLICT = 0 in r6).
// fmt bit0/1: C0/C1 as fp16 stride-256; else fp32 stride-N

__global__ __launch_bounds__(512, 4) void gemm_pair(
    const u16* __restrict__ A, int Kp,
    const u16* __restrict__ B0, const u16* __restrict__ B1,
    const float* __restrict__ bias0, const float* __restrict__ bias1,
    void* __restrict__ C0v, void* __restrict__ C1v, int M, int N, int fmt)
{
    __shared__ u16 AS[2][128][32], B0S[2][128][32], B1S[2][128][32];  // 48 KB

    int row0 = blockIdx.x * 128;
    int col0 = blockIdx.y * 128;
    int t = threadIdx.x;
    int lane = t & 63, w = t >> 6;
    int wr = w >> 2, wc = w & 3;            // 2 x 4 wave grid -> 64 rows x 32 cols
    int quad = lane >> 4, rr = lane & 15;
    int rcol = (quad ^ ((rr >> 1) & 3)) * 8;   // swizzled read column (u16)

    f32x4 acc0[4][2], acc1[4][2];
#pragma unroll
    for (int i = 0; i < 4; i++)
#pragma unroll
        for (int j = 0; j < 2; j++) {
            acc0[i][j] = (f32x4){0.f, 0.f, 0.f, 0.f};
            acc1[i][j] = (f32x4){0.f, 0.f, 0.f, 0.f};
        }

    // staging: row sr = t>>2 (0..127), granule sg = t&3; ONE 16B chunk per array
    int sr = t >> 2, sg = t & 3;
    int scol = (sg ^ ((sr >> 1) & 3)) * 8;   // swizzled write column
    bool aok = (row0 + sr) < M;
    const u16* pA  = A  + (size_t)(row0 + sr) * Kp + sg * 8;
    const u16* pB0 = B0 + (size_t)(col0 + sr) * Kp + sg * 8;
    const u16* pB1 = B1 + (size_t)(col0 + sr) * Kp + sg * 8;

    // prologue: stage k0=0 into buffer 0
    {
        f16x8 ra{};
        if (aok) ra = *(const f16x8*)pA;
        f16x8 rb0 = *(const f16x8*)pB0;
        f16x8 rb1 = *(const f16x8*)pB1;
        *(f16x8*)&AS[0][sr][scol]  = ra;
        *(f16x8*)&B0S[0][sr][scol] = rb0;
        *(f16x8*)&B1S[0][sr][scol] = rb1;
    }
    __syncthreads();

    int cur = 0;
    for (int k0 = 0; k0 < Kp; k0 += 32) {
        int kn = k0 + 32;
        bool more = kn < Kp;
        // issue next K-step's global loads EARLY (latency hides under MFMA phase)
        f16x8 ra{}, rb0{}, rb1{};
        if (more) {
            if (aok) ra = *(const f16x8*)(pA + kn);
            rb0 = *(const f16x8*)(pB0 + kn);
            rb1 = *(const f16x8*)(pB1 + kn);
        }

        // ---- compute current buffer ----
        f16x8 fA[4];
#pragma unroll
        for (int fi = 0; fi < 4; fi++) {
            int r = wr * 64 + fi * 16 + rr;
            fA[fi] = *(const f16x8*)&AS[cur][r][rcol];
        }
#pragma unroll
        for (int fj = 0; fj < 2; fj++) {
            int c = wc * 32 + fj * 16 + rr;
            f16x8 b0 = *(const f16x8*)&B0S[cur][c][rcol];
            f16x8 b1 = *(const f16x8*)&B1S[cur][c][rcol];
#pragma unroll
            for (int fi = 0; fi < 4; fi++) {
                acc0[fi][fj] = __builtin_amdgcn_mfma_f32_16x16x32_f16(fA[fi], b0, acc0[fi][fj], 0, 0, 0);
                acc1[fi][fj] = __builtin_amdgcn_mfma_f32_16x16x32_f16(fA[fi], b1, acc1[fi][fj], 0, 0, 0);
            }
        }

        // write next buffer late; one barrier per K-step
        if (more) {
            int nb_ = cur ^ 1;
            *(f16x8*)&AS[nb_][sr][scol]  = ra;
            *(f16x8*)&B0S[nb_][sr][scol] = rb0;
            *(f16x8*)&B1S[nb_][sr][scol] = rb1;
            __syncthreads();
            cur = nb_;
        }
    }

#pragma unroll
    for (int fj = 0; fj < 2; fj++) {
        int gc = col0 + wc * 32 + fj * 16 + rr;
        if (gc >= N) continue;
        float bb0 = bias0 ? bias0[gc] : 0.f;
        float bb1 = bias1 ? bias1[gc] : 0.f;
#pragma unroll
        for (int fi = 0; fi < 4; fi++) {
#pragma unroll
            for (int r = 0; r < 4; r++) {
                int grr = row0 + wr * 64 + fi * 16 + quad * 4 + r;
                if (grr < M) {
                    float v0 = acc0[fi][fj][r] + bb0;
                    float v1 = acc1[fi][fj][r] + bb1;
                    if (fmt & 1) ((u16*)C0v)[(size_t)grr * 256 + gc] = f2h(v0);
                    else         ((float*)C0v)[(size_t)grr * N + gc] = v0;
                    if (fmt & 2) ((u16*)C1v)[(size_t)grr * 256 + gc] = f2h(v1);
                    else         ((float*)C1v)[(size_t)grr * N + gc] = v1;
                }
            }
        }
    }
}

// ---------------- fused edge phase: packed-fp16 single-pass softmax+aggregate ----------------
// r4 structure (1 node/wave, 2-deep gather pipeline) — at its measured plateau.

__global__ __launch_bounds__(256) void fused_edge_kernel(
    const int* __restrict__ rowptr, const int* __restrict__ ssrc,
    const u16* __restrict__ xl16, const u16* __restrict__ xr16,
    const u16* __restrict__ atth,
    u16* __restrict__ Oh, int dorelu)
{
    int i = blockIdx.x * 4 + (threadIdx.x >> 6);
    if (i >= NN) return;
    int lane = threadIdx.x & 63;
    int d0 = lane * 4;
    int lb = d0 * 2;                 // lane byte offset into fp16 row

    uint2 atr = *(const uint2*)&atth[d0];
    h2v at0h = *(h2v*)&atr.x, at1h = *(h2v*)&atr.y;
    const h2v c02 = {(_Float16)0.2f, (_Float16)0.2f};
    const char* xlb = (const char*)xl16;

    uint2 xrr = *(const uint2*)&xr16[(size_t)i * 256 + d0];
    h2v xr0h = *(h2v*)&xrr.x, xr1h = *(h2v*)&xrr.y;

    int beg = __builtin_amdgcn_readfirstlane(rowptr[i]);
    int end = __builtin_amdgcn_readfirstlane(rowptr[i + 1]);

    float m = -1e30f, ssum = 0.f;
    float4 acc = make_float4(0.f, 0.f, 0.f, 0.f);

    auto ldrow = [&](int o) -> uint2 {
        return *(const uint2*)(xlb + o + lb);
    };
    auto edge_score = [&](uint2 g) -> float {
        h2v x0 = *(h2v*)&g.x, x1 = *(h2v*)&g.y;
        h2v s = x0 + xr0h; s = hmax2v(s, s * c02);
        float e = __builtin_amdgcn_fdot2(s, at0h, 0.f, false);
        s = x1 + xr1h; s = hmax2v(s, s * c02);
        return __builtin_amdgcn_fdot2(s, at1h, e, false);
    };
    auto single_update = [&](uint2 g) {
        float e = f32_wave_sum63(edge_score(g));
        h2v x0 = *(h2v*)&g.x, x1 = *(h2v*)&g.y;
        float nm = fmaxf(m, e);
        float sc = __expf(m - nm);
        float w = __expf(e - nm);
        acc.x = fmaf(w, (float)x0.x, acc.x * sc);
        acc.y = fmaf(w, (float)x0.y, acc.y * sc);
        acc.z = fmaf(w, (float)x1.x, acc.z * sc);
        acc.w = fmaf(w, (float)x1.y, acc.w * sc);
        ssum = fmaf(ssum, sc, w);
        m = nm;
    };

    int p = beg;
    if (p + 3 < end) {
        // ---- prologue: block A gathers, block B gathers, block C offsets ----
        int o0 = __builtin_amdgcn_readfirstlane(ssrc[p]);
        int o1 = __builtin_amdgcn_readfirstlane(ssrc[p + 1]);
        int o2 = __builtin_amdgcn_readfirstlane(ssrc[p + 2]);
        int o3 = __builtin_amdgcn_readfirstlane(ssrc[p + 3]);
        uint2 a0 = ldrow(o0), a1 = ldrow(o1), a2 = ldrow(o2), a3 = ldrow(o3);

        bool hB = (p + 7 < end);
        uint2 b0, b1, b2, b3;
        if (hB) {
            int q0 = __builtin_amdgcn_readfirstlane(ssrc[p + 4]);
            int q1 = __builtin_amdgcn_readfirstlane(ssrc[p + 5]);
            int q2 = __builtin_amdgcn_readfirstlane(ssrc[p + 6]);
            int q3 = __builtin_amdgcn_readfirstlane(ssrc[p + 7]);
            b0 = ldrow(q0); b1 = ldrow(q1); b2 = ldrow(q2); b3 = ldrow(q3);
        }
        bool hC = (p + 11 < end);
        int co0 = 0, co1 = 0, co2 = 0, co3 = 0;
        if (hC) {
            co0 = __builtin_amdgcn_readfirstlane(ssrc[p + 8]);
            co1 = __builtin_amdgcn_readfirstlane(ssrc[p + 9]);
            co2 = __builtin_amdgcn_readfirstlane(ssrc[p + 10]);
            co3 = __builtin_amdgcn_readfirstlane(ssrc[p + 11]);
        }

        for (;;) {
            // issue block-C gathers (2 blocks ahead of compute)
            uint2 cg0, cg1, cg2, cg3;
            if (hC) {
                cg0 = ldrow(co0); cg1 = ldrow(co1); cg2 = ldrow(co2); cg3 = ldrow(co3);
            }
            // fetch block-D offsets
            bool hD = (p + 15 < end);
            int do0 = 0, do1 = 0, do2 = 0, do3 = 0;
            if (hD) {
                do0 = __builtin_amdgcn_readfirstlane(ssrc[p + 12]);
                do1 = __builtin_amdgcn_readfirstlane(ssrc[p + 13]);
                do2 = __builtin_amdgcn_readfirstlane(ssrc[p + 14]);
                do3 = __builtin_amdgcn_readfirstlane(ssrc[p + 15]);
            }

            // ---- compute block A ----
            h2v x00 = *(h2v*)&a0.x, x01 = *(h2v*)&a0.y;
            h2v x10 = *(h2v*)&a1.x, x11 = *(h2v*)&a1.y;
            h2v x20 = *(h2v*)&a2.x, x21 = *(h2v*)&a2.y;
            h2v x30 = *(h2v*)&a3.x, x31 = *(h2v*)&a3.y;

            h2v s;
            float e0, e1, e2, e3;
            s = x00 + xr0h; s = hmax2v(s, s * c02);
            e0 = __builtin_amdgcn_fdot2(s, at0h, 0.f, false);
            s = x01 + xr1h; s = hmax2v(s, s * c02);
            e0 = __builtin_amdgcn_fdot2(s, at1h, e0, false);
            s = x10 + xr0h; s = hmax2v(s, s * c02);
            e1 = __builtin_amdgcn_fdot2(s, at0h, 0.f, false);
            s = x11 + xr1h; s = hmax2v(s, s * c02);
            e1 = __builtin_amdgcn_fdot2(s, at1h, e1, false);
            s = x20 + xr0h; s = hmax2v(s, s * c02);
            e2 = __builtin_amdgcn_fdot2(s, at0h, 0.f, false);
            s = x21 + xr1h; s = hmax2v(s, s * c02);
            e2 = __builtin_amdgcn_fdot2(s, at1h, e2, false);
            s = x30 + xr0h; s = hmax2v(s, s * c02);
            e3 = __builtin_amdgcn_fdot2(s, at0h, 0.f, false);
            s = x31 + xr1h; s = hmax2v(s, s * c02);
            e3 = __builtin_amdgcn_fdot2(s, at1h, e3, false);

            // packed-pair DPP reduce: two independent VALU chains
            H2U u01, u23, r01, r23;
            u01.h.x = (_Float16)e0; u01.h.y = (_Float16)e1;
            u23.h.x = (_Float16)e2; u23.h.y = (_Float16)e3;
            r01.u = h2_wave_sum63(u01.h);
            r23.u = h2_wave_sum63(u23.h);
            float es0 = (float)r01.h.x, es1 = (float)r01.h.y;
            float es2 = (float)r23.h.x, es3 = (float)r23.h.y;

            float nm = fmaxf(fmaxf(m, es0), fmaxf(fmaxf(es1, es2), es3));
            float sc = __expf(m - nm);
            float w0 = __expf(es0 - nm);
            float w1 = __expf(es1 - nm);
            float w2 = __expf(es2 - nm);
            float w3 = __expf(es3 - nm);
            float ax0 = fmaf(w1, (float)x10.x, w0 * (float)x00.x);
            float ax1 = fmaf(w3, (float)x30.x, w2 * (float)x20.x);
            float ay0 = fmaf(w1, (float)x10.y, w0 * (float)x00.y);
            float ay1 = fmaf(w3, (float)x30.y, w2 * (float)x20.y);
            float az0 = fmaf(w1, (float)x11.x, w0 * (float)x01.x);
            float az1 = fmaf(w3, (float)x31.x, w2 * (float)x21.x);
            float aw0 = fmaf(w1, (float)x11.y, w0 * (float)x01.y);
            float aw1 = fmaf(w3, (float)x31.y, w2 * (float)x21.y);
            acc.x = fmaf(acc.x, sc, ax0 + ax1);
            acc.y = fmaf(acc.y, sc, ay0 + ay1);
            acc.z = fmaf(acc.z, sc, az0 + az1);
            acc.w = fmaf(acc.w, sc, aw0 + aw1);
            ssum = fmaf(ssum, sc, (w0 + w1) + (w2 + w3));
            m = nm;

            p += 4;
            if (!hB) break;
            // rotate pipeline: A <- B <- C; C-offsets <- D-offsets
            a0 = b0; a1 = b1; a2 = b2; a3 = b3;
            b0 = cg0; b1 = cg1; b2 = cg2; b3 = cg3;
            hB = hC; hC = hD;
            co0 = do0; co1 = do1; co2 = do2; co3 = do3;
        }
    }

    // remainder (0..3 edges): hoist gathers ahead of processing
    int rem = end - p;
    if (rem > 0) {
        int o0 = __builtin_amdgcn_readfirstlane(ssrc[p]);
        int o1 = 0, o2 = 0;
        if (rem > 1) o1 = __builtin_amdgcn_readfirstlane(ssrc[p + 1]);
        if (rem > 2) o2 = __builtin_amdgcn_readfirstlane(ssrc[p + 2]);
        uint2 g0 = ldrow(o0);
        uint2 g1, g2;
        if (rem > 1) g1 = ldrow(o1);
        if (rem > 2) g2 = ldrow(o2);
        single_update(g0);
        if (rem > 1) single_update(g1);
        if (rem > 2) single_update(g2);
    }

    float inv = 1.f / ssum;
    acc.x *= inv; acc.y *= inv; acc.z *= inv; acc.w *= inv;
    if (dorelu) {
        acc.x = fmaxf(acc.x, 0.f); acc.y = fmaxf(acc.y, 0.f);
        acc.z = fmaxf(acc.z, 0.f); acc.w = fmaxf(acc.w, 0.f);
    }
    size_t obase = (size_t)i * 256 + d0;
    ushort4 hv;
    hv.x = f2h(acc.x); hv.y = f2h(acc.y); hv.z = f2h(acc.z); hv.w = f2h(acc.w);
    *(ushort4*)&Oh[obase] = hv;   // pad lanes harmless; B k-pads are zero
}

// ---------------- query head: 4 queries per wave; 8 gathers in flight ----------------

__global__ __launch_bounds__(256) void query_kernel(
    const int* __restrict__ qry, const u16* __restrict__ Ptop,
    const u16* __restrict__ Pbot, const float* __restrict__ Wm2,
    const float* __restrict__ bm2, float* __restrict__ out)
{
    int q = (blockIdx.x * 4 + (threadIdx.x >> 6)) * 4;
    if (q >= NQ) return;
    int lane = threadIdx.x & 63;
    int a0 = __builtin_amdgcn_readfirstlane(qry[q * 2 + 0]);
    int b0 = __builtin_amdgcn_readfirstlane(qry[q * 2 + 1]);
    int a1 = __builtin_amdgcn_readfirstlane(qry[q * 2 + 2]);
    int b1 = __builtin_amdgcn_readfirstlane(qry[q * 2 + 3]);
    int a2 = __builtin_amdgcn_readfirstlane(qry[q * 2 + 4]);
    int b2 = __builtin_amdgcn_readfirstlane(qry[q * 2 + 5]);
    int a3 = __builtin_amdgcn_readfirstlane(qry[q * 2 + 6]);
    int b3 = __builtin_amdgcn_readfirstlane(qry[q * 2 + 7]);
    float4 w  = *(const float4*)&Wm2[lane * 4];
    float4 t0 = ld4h(&Ptop[(size_t)a0 * HD + lane * 4]);
    float4 v0 = ld4h(&Pbot[(size_t)b0 * HD + lane * 4]);
    float4 t1 = ld4h(&Ptop[(size_t)a1 * HD + lane * 4]);
    float4 v1 = ld4h(&Pbot[(size_t)b1 * HD + lane * 4]);
    float4 t2 = ld4h(&Ptop[(size_t)a2 * HD + lane * 4]);
    float4 v2 = ld4h(&Pbot[(size_t)b2 * HD + lane * 4]);
    float4 t3 = ld4h(&Ptop[(size_t)a3 * HD + lane * 4]);
    float4 v3 = ld4h(&Pbot[(size_t)b3 * HD + lane * 4]);
    float s0 = fmaxf(t0.x + v0.x, 0.f) * w.x + fmaxf(t0.y + v0.y, 0.f) * w.y
             + fmaxf(t0.z + v0.z, 0.f) * w.z + fmaxf(t0.w + v0.w, 0.f) * w.w;
    float s1 = fmaxf(t1.x + v1.x, 0.f) * w.x + fmaxf(t1.y + v1.y, 0.f) * w.y
             + fmaxf(t1.z + v1.z, 0.f) * w.z + fmaxf(t1.w + v1.w, 0.f) * w.w;
    float s2 = fmaxf(t2.x + v2.x, 0.f) * w.x + fmaxf(t2.y + v2.y, 0.f) * w.y
             + fmaxf(t2.z + v2.z, 0.f) * w.z + fmaxf(t2.w + v2.w, 0.f) * w.w;
    float s3 = fmaxf(t3.x + v3.x, 0.f) * w.x + fmaxf(t3.y + v3.y, 0.f) * w.y
             + fmaxf(t3.z + v3.z, 0.f) * w.z + fmaxf(t3.w + v3.w, 0.f) * w.w;
    s0 = f32_wave_sum63(s0);
    s1 = f32_wave_sum63(s1);
    s2 = f32_wave_sum63(s2);
    s3 = f32_wave_sum63(s3);
    if (lane == 0) {
        float bb = bm2[0];
        out[q]     = fmaxf(s0 + bb, 0.f);
        out[q + 1] = fmaxf(s1 + bb, 0.f);
        out[q + 2] = fmaxf(s2 + bb, 0.f);
        out[q + 3] = fmaxf(s3 + bb, 0.f);
    }
}

// ---------------- launch ----------------

extern "C" void kernel_launch(void* const* d_in, const int* in_sizes, int n_in,
                              void* d_out, int out_size, void* d_ws, size_t ws_size,
                              hipStream_t stream) {
    const float* x    = (const float*)d_in[0];
    const int*   ei   = (const int*)d_in[1];
    const int*   qry  = (const int*)d_in[2];
    const float* W1l  = (const float*)d_in[3];
    const float* b1l  = (const float*)d_in[4];
    const float* W1r  = (const float*)d_in[5];
    const float* b1r  = (const float*)d_in[6];
    const float* att1 = (const float*)d_in[7];
    const float* W2l  = (const float*)d_in[8];
    const float* b2l  = (const float*)d_in[9];
    const float* W2r  = (const float*)d_in[10];
    const float* b2r  = (const float*)d_in[11];
    const float* att2 = (const float*)d_in[12];
    const float* Wm1  = (const float*)d_in[13];
    const float* bm1  = (const float*)d_in[14];
    const float* Wm2  = (const float*)d_in[15];
    const float* bm2  = (const float*)d_in[16];
    float* out = (float*)d_out;

    // workspace carve-up (all node tensors fp16 stride-256)
    u16* xl16    = (u16*)d_ws;                   // NN*256 halfs (25.6 MB)
    u16* xr16    = xl16 + (size_t)NN * 256;      // NN*256 halfs (25.6 MB)
    int* rowptr  = (int*)(xr16 + (size_t)NN * 256);  // NN+1
    int* fill    = rowptr + NN + 1;              // NN (count buffer)
    int* ssrc    = fill + NN;                    // ET
    int* bsum    = ssrc + ET;                    // 256
    u16* atth1   = (u16*)(bsum + 256);           // 256 halfs
    u16* atth2   = atth1 + 256;                  // 256 halfs
    uintptr_t wp = (uintptr_t)(atth2 + 256);
    wp = (wp + 63) & ~(uintptr_t)63;
    u16* W1lT = (u16*)wp;                        // 256*128 each
    u16* W1rT = W1lT + 256 * 128;
    u16* W2lT = W1rT + 256 * 128;                // 256*256 each from here
    u16* W2rT = W2lT + 65536;
    u16* WmtT = W2rT + 65536;
    u16* WmbT = WmtT + 65536;
    u16* Asp  = WmbT + 65536;                    // NN*256 fp16
    u16* Ptop16 = xl16;                          // head overlays (dead after layer-2)
    u16* Pbot16 = xr16;

    dim3 blk(256);
    int gET = (ET + 255) / 256;
    int gNode = (NN + 3) / 4;                    // 4 waves/block, 1 node/wave
    int nb = (NN + 255) / 256;                   // 196 scan blocks
    dim3 gg((NN + 127) / 128, 2);                // 782 gemm blocks (128x128 tiles)

    // ---- zero degree counters (graph-capture-safe), then conversions + count ----
    hipMemsetAsync(fill, 0, (size_t)NN * sizeof(int), stream);
    conv_all<<<CONVX_BLOCKS + 1282 + gET, blk, 0, stream>>>(x, ei, Asp,
        W1l, W1r, W2l, W2r, Wm1, att1, att2,
        W1lT, W1rT, W2lT, W2rT, WmtT, WmbT, atth1, atth2, fill);

    // ---- CSR build (parallel 3-dispatch scan) ----
    scan1_kernel<<<nb, blk, 0, stream>>>(fill, rowptr, bsum);   // also zeroes fill
    scan2_kernel<<<1, blk, 0, stream>>>(bsum, rowptr, nb);
    scan3_kernel<<<nb, blk, 0, stream>>>(rowptr, bsum);
    scatter_kernel<<<gET, blk, 0, stream>>>(ei, rowptr, fill, ssrc);

    // ---- layer 1 (A = x fp16, Kp=128): both outputs fp16 stride-256 ----
    gemm_pair<<<gg, dim3(512), 0, stream>>>(Asp, 128, W1lT, W1rT,
                                      b1l, b1r, (void*)xl16, (void*)xr16, NN, DD, 3);
    fused_edge_kernel<<<gNode, blk, 0, stream>>>(rowptr, ssrc, xl16, xr16, atth1, Asp, 1);

    // ---- layer 2 (A = h fp16, Kp=256) ----
    gemm_pair<<<gg, dim3(512), 0, stream>>>(Asp, 256, W2lT, W2rT,
                                      b2l, b2r, (void*)xl16, (void*)xr16, NN, DD, 3);
    fused_edge_kernel<<<gNode, blk, 0, stream>>>(rowptr, ssrc, xl16, xr16, atth2, Asp, 0);

    // ---- head precompute (A = emb fp16, Kp=256): both outputs fp16 ----
    gemm_pair<<<gg, dim3(512), 0, stream>>>(Asp, 256, WmtT, WmbT,
                                      bm1, (const float*)nullptr, (void*)Ptop16, (void*)Pbot16, NN, HD, 3);

    // ---- per-query head ----
    query_kernel<<<(NQ / 4 + 3) / 4, blk, 0, stream>>>(qry, Ptop16, Pbot16, Wm2, bm2, out);
}

// Round 8
// 426.110 us; speedup vs baseline: 1.4121x; 1.0694x over previous
//
#include <hip/hip_runtime.h>
#include <hip/hip_fp16.h>
#include <math.h>
#include <stdint.h>

#define NN 50000
#define NE 800000
#define ET (NE + NN)      // 850000 edges incl self loops
#define FIN 128
#define DD 250
#define HD 256
#define NQ 200000
#define NEG_SLOPE 0.2f

typedef unsigned short u16;
typedef __attribute__((ext_vector_type(4))) float f32x4;
typedef _Float16 h2v __attribute__((ext_vector_type(2)));
typedef _Float16 f16x8 __attribute__((ext_vector_type(8)));

union H2U { h2v h; unsigned int u; };

__device__ __forceinline__ u16 f2h(float v) {
    __half h = __float2half(v);
    return *reinterpret_cast<u16*>(&h);
}
// load 4 fp16 (8B) -> float4 (used by query kernel)
__device__ __forceinline__ float4 ld4h(const u16* p) {
    uint2 r = *(const uint2*)p;
    __half2 a = *(__half2*)&r.x;
    __half2 b = *(__half2*)&r.y;
    float2 fa = __half22float2(a), fb = __half22float2(b);
    return make_float4(fa.x, fa.y, fb.x, fb.y);
}
// packed fp16 max -> v_pk_max_f16
__device__ __forceinline__ h2v hmax2v(h2v a, h2v b) {
    return __builtin_elementwise_max(a, b);
}

// ---------------- DPP wave-64 reductions (VALU pipe, no LDS/bpermute) ----------------

#define DPPMOV(v, ctrl, rm) \
    ((unsigned int)__builtin_amdgcn_update_dpp(0, (int)(v), (ctrl), (rm), 0xF, true))

// packed fp16 pair sum across 64 lanes; result via readlane(63)
__device__ __forceinline__ unsigned int h2_wave_sum63(h2v x) {
    H2U u, t; u.h = x;
    t.u = DPPMOV(u.u, 0x111, 0xF); u.h = u.h + t.h;   // row_shr:1
    t.u = DPPMOV(u.u, 0x112, 0xF); u.h = u.h + t.h;   // row_shr:2
    t.u = DPPMOV(u.u, 0x114, 0xF); u.h = u.h + t.h;   // row_shr:4
    t.u = DPPMOV(u.u, 0x118, 0xF); u.h = u.h + t.h;   // row_shr:8
    t.u = DPPMOV(u.u, 0x142, 0xA); u.h = u.h + t.h;   // row_bcast:15 -> rows 1,3
    t.u = DPPMOV(u.u, 0x143, 0xC); u.h = u.h + t.h;   // row_bcast:31 -> rows 2,3
    return (unsigned int)__builtin_amdgcn_readlane((int)u.u, 63);
}

// fp32 sum across 64 lanes, result uniform (readlane 63)
__device__ __forceinline__ float f32_wave_sum63(float x) {
    union FU { float f; unsigned int u; } a, t, o;
    a.f = x;
    t.u = DPPMOV(a.u, 0x111, 0xF); a.f += t.f;
    t.u = DPPMOV(a.u, 0x112, 0xF); a.f += t.f;
    t.u = DPPMOV(a.u, 0x114, 0xF); a.f += t.f;
    t.u = DPPMOV(a.u, 0x118, 0xF); a.f += t.f;
    t.u = DPPMOV(a.u, 0x142, 0xA); a.f += t.f;
    t.u = DPPMOV(a.u, 0x143, 0xC); a.f += t.f;
    o.u = (unsigned int)__builtin_amdgcn_readlane((int)a.u, 63);
    return o.f;
}

// ---------------- CSR build (2-dispatch scan; scan2 folded into scan3) ----------------

__global__ __launch_bounds__(256) void scan1_kernel(
    int* __restrict__ cnt, int* __restrict__ rowptr, int* __restrict__ bsum)
{
    __shared__ int buf[256];
    int t = threadIdx.x;
    int i = blockIdx.x * 256 + t;
    int v = (i < NN) ? cnt[i] : 0;
    if (i < NN) cnt[i] = 0;          // zero fill for scatter
    buf[t] = v;
    __syncthreads();
#pragma unroll
    for (int off = 1; off < 256; off <<= 1) {
        int add = (t >= off) ? buf[t - off] : 0;
        __syncthreads();
        buf[t] += add;
        __syncthreads();
    }
    if (i < NN) rowptr[i] = buf[t] - v;     // block-local exclusive
    if (t == 255) bsum[blockIdx.x] = buf[255];
}

// scan3': each block re-scans bsum internally (nb<=256) -> no separate scan2 pass
__global__ __launch_bounds__(256) void scan3_kernel(
    int* __restrict__ rowptr, const int* __restrict__ bsum, int nb)
{
    __shared__ int buf[256];
    int t = threadIdx.x;
    int v = (t < nb) ? bsum[t] : 0;
    buf[t] = v;
    __syncthreads();
#pragma unroll
    for (int off = 1; off < 256; off <<= 1) {
        int add = (t >= off) ? buf[t - off] : 0;
        __syncthreads();
        buf[t] += add;
        __syncthreads();
    }
    int boff = (blockIdx.x == 0) ? 0 : buf[blockIdx.x - 1];  // exclusive prefix of this block
    int i = blockIdx.x * 256 + t;
    if (i < NN) rowptr[i] += boff;
    if (blockIdx.x == 0 && t == 0) rowptr[NN] = buf[nb - 1];
}

// stores premultiplied src BYTE offset (s*512, fp16-row stride) for the fused kernel
__global__ void scatter_kernel(const int* __restrict__ ei,
                               const int* __restrict__ rowptr,
                               int* __restrict__ fill,
                               int* __restrict__ ssrc) {
    int k = blockIdx.x * 256 + threadIdx.x;
    if (k >= ET) return;
    int s, d;
    if (k < NE) { s = ei[k]; d = ei[NE + k]; }
    else        { s = k - NE; d = k - NE; }
    int pos = rowptr[d] + atomicAdd(&fill[d], 1);
    ssrc[pos] = s << 9;
}

// ---------------- combined conversion + degree-count kernel ----------------

#define CONVX_BLOCKS 3125

__global__ __launch_bounds__(256) void conv_all(
    const float* __restrict__ x, const int* __restrict__ ei,
    u16* __restrict__ Asp,
    const float* __restrict__ W1l, const float* __restrict__ W1r,
    const float* __restrict__ W2l, const float* __restrict__ W2r,
    const float* __restrict__ Wm1,
    const float* __restrict__ att1, const float* __restrict__ att2,
    u16* __restrict__ W1lT, u16* __restrict__ W1rT,
    u16* __restrict__ W2lT, u16* __restrict__ W2rT,
    u16* __restrict__ WmtT, u16* __restrict__ WmbT,
    u16* __restrict__ atth1, u16* __restrict__ atth2,
    int* __restrict__ cnt)
{
    if (blockIdx.x < CONVX_BLOCKS) {
        int tid = blockIdx.x * 256 + threadIdx.x;
        size_t idx = (size_t)tid * 8;
        if (idx >= (size_t)NN * FIN) return;
        float4 v0 = *(const float4*)(x + idx);
        float4 v1 = *(const float4*)(x + idx + 4);
        ushort4 o0, o1;
        o0.x = f2h(v0.x); o0.y = f2h(v0.y); o0.z = f2h(v0.z); o0.w = f2h(v0.w);
        o1.x = f2h(v1.x); o1.y = f2h(v1.y); o1.z = f2h(v1.z); o1.w = f2h(v1.w);
        *(ushort4*)(Asp + idx) = o0;
        *(ushort4*)(Asp + idx + 4) = o1;
        return;
    }
    int b = blockIdx.x - CONVX_BLOCKS;
    if (b < 1280) {
        const float* W; int K, N, koff, kshift, b0; u16* ot;
        if (b < 128)       { W = W1l; K = FIN; N = DD; koff = 0;  kshift = 7; b0 = 0;    ot = W1lT; }
        else if (b < 256)  { W = W1r; K = FIN; N = DD; koff = 0;  kshift = 7; b0 = 128;  ot = W1rT; }
        else if (b < 512)  { W = W2l; K = DD;  N = DD; koff = 0;  kshift = 8; b0 = 256;  ot = W2lT; }
        else if (b < 768)  { W = W2r; K = DD;  N = DD; koff = 0;  kshift = 8; b0 = 512;  ot = W2rT; }
        else if (b < 1024) { W = Wm1; K = DD;  N = HD; koff = 0;  kshift = 8; b0 = 768;  ot = WmtT; }
        else               { W = Wm1; K = DD;  N = HD; koff = DD; kshift = 8; b0 = 1024; ot = WmbT; }
        int id = (b - b0) * 256 + threadIdx.x;
        int Kp = 1 << kshift;
        int n = id >> kshift, k = id & (Kp - 1);
        float v = (n < N && k < K) ? W[(size_t)(k + koff) * N + n] : 0.f;
        ot[id] = f2h(v);
        return;
    }
    if (b < 1282) {
        const float* a = (b == 1280) ? att1 : att2;
        u16* o = (b == 1280) ? atth1 : atth2;
        int id = threadIdx.x;
        o[id] = f2h(id < DD ? a[id] : 0.f);
        return;
    }
    // degree count
    int k = (b - 1282) * 256 + threadIdx.x;
    if (k >= ET) return;
    int d = (k < NE) ? ei[NE + k] : (k - NE);
    atomicAdd(&cnt[d], 1);
}

// ---------------- fp16 MFMA pair-GEMM v6 ----------------
// v5 structure (128x128 tile, 512 thr, 8 waves 2x4 of 64x32, dbuf + XOR swizzle,
// launch_bounds(512,4) -> 2 blocks/CU) + NEW coalesced epilogue:
// r6 counters showed WRITE_SIZE 90.9MB vs 51.2 ideal (32B-fragment C-writes ->
// partial-line amplification). v6 stages each output's 128x128 fp16 tile in
// reused LDS (stride 136 u16: 16B-aligned rows, conflict-free col writes) and
// streams it out as full 256B-contiguous rows. N-pad cols get clean zeros.
// NOTE: fmt param ignored — all callers use fp16 stride-256 outputs.

__global__ __launch_bounds__(512, 4) void gemm_pair(
    const u16* __restrict__ A, int Kp,
    const u16* __restrict__ B0, const u16* __restrict__ B1,
    const float* __restrict__ bias0, const float* __restrict__ bias1,
    void* __restrict__ C0v, void* __restrict__ C1v, int M, int N, int fmt)
{
    __shared__ u16 SM[2][3][128][32];   // [kbuf][A/B0/B1][row][col] = 48 KB

    int row0 = blockIdx.x * 128;
    int col0 = blockIdx.y * 128;
    int t = threadIdx.x;
    int lane = t & 63, w = t >> 6;
    int wr = w >> 2, wc = w & 3;            // 2 x 4 wave grid -> 64 rows x 32 cols
    int quad = lane >> 4, rr = lane & 15;
    int rcol = (quad ^ ((rr >> 1) & 3)) * 8;   // swizzled read column (u16)

    f32x4 acc0[4][2], acc1[4][2];
#pragma unroll
    for (int i = 0; i < 4; i++)
#pragma unroll
        for (int j = 0; j < 2; j++) {
            acc0[i][j] = (f32x4){0.f, 0.f, 0.f, 0.f};
            acc1[i][j] = (f32x4){0.f, 0.f, 0.f, 0.f};
        }

    // staging: row sr = t>>2 (0..127), granule sg = t&3; ONE 16B chunk per array
    int sr = t >> 2, sg = t & 3;
    int scol = (sg ^ ((sr >> 1) & 3)) * 8;   // swizzled write column
    bool aok = (row0 + sr) < M;
    const u16* pA  = A  + (size_t)(row0 + sr) * Kp + sg * 8;
    const u16* pB0 = B0 + (size_t)(col0 + sr) * Kp + sg * 8;
    const u16* pB1 = B1 + (size_t)(col0 + sr) * Kp + sg * 8;

    // prologue: stage k0=0 into buffer 0
    {
        f16x8 ra{};
        if (aok) ra = *(const f16x8*)pA;
        f16x8 rb0 = *(const f16x8*)pB0;
        f16x8 rb1 = *(const f16x8*)pB1;
        *(f16x8*)&SM[0][0][sr][scol] = ra;
        *(f16x8*)&SM[0][1][sr][scol] = rb0;
        *(f16x8*)&SM[0][2][sr][scol] = rb1;
    }
    __syncthreads();

    int cur = 0;
    for (int k0 = 0; k0 < Kp; k0 += 32) {
        int kn = k0 + 32;
        bool more = kn < Kp;
        // issue next K-step's global loads EARLY (latency hides under MFMA phase)
        f16x8 ra{}, rb0{}, rb1{};
        if (more) {
            if (aok) ra = *(const f16x8*)(pA + kn);
            rb0 = *(const f16x8*)(pB0 + kn);
            rb1 = *(const f16x8*)(pB1 + kn);
        }

        // ---- compute current buffer ----
        f16x8 fA[4];
#pragma unroll
        for (int fi = 0; fi < 4; fi++) {
            int r = wr * 64 + fi * 16 + rr;
            fA[fi] = *(const f16x8*)&SM[cur][0][r][rcol];
        }
#pragma unroll
        for (int fj = 0; fj < 2; fj++) {
            int c = wc * 32 + fj * 16 + rr;
            f16x8 b0 = *(const f16x8*)&SM[cur][1][c][rcol];
            f16x8 b1 = *(const f16x8*)&SM[cur][2][c][rcol];
#pragma unroll
            for (int fi = 0; fi < 4; fi++) {
                acc0[fi][fj] = __builtin_amdgcn_mfma_f32_16x16x32_f16(fA[fi], b0, acc0[fi][fj], 0, 0, 0);
                acc1[fi][fj] = __builtin_amdgcn_mfma_f32_16x16x32_f16(fA[fi], b1, acc1[fi][fj], 0, 0, 0);
            }
        }

        // write next buffer late; one barrier per K-step
        if (more) {
            int nb_ = cur ^ 1;
            *(f16x8*)&SM[nb_][0][sr][scol] = ra;
            *(f16x8*)&SM[nb_][1][sr][scol] = rb0;
            *(f16x8*)&SM[nb_][2][sr][scol] = rb1;
            __syncthreads();
            cur = nb_;
        }
    }

    // ---- coalesced epilogue: stage fp16 tile in LDS, stream full rows ----
    __syncthreads();                                   // all K-loop LDS reads done
    u16 (*CS)[136] = (u16 (*)[136])&SM[0][0][0][0];    // 128 x 136 u16 = 34 KB

#pragma unroll
    for (int which = 0; which < 2; ++which) {
        const float* bias = which ? bias1 : bias0;
        u16* Cout = (u16*)(which ? C1v : C0v);
#pragma unroll
        for (int fj = 0; fj < 2; fj++) {
            int c = wc * 32 + fj * 16 + rr;
            int gc = col0 + c;
            bool cok = gc < N;
            float bb = (bias && cok) ? bias[gc] : 0.f;
#pragma unroll
            for (int fi = 0; fi < 4; fi++) {
#pragma unroll
                for (int r = 0; r < 4; r++) {
                    int row = wr * 64 + fi * 16 + quad * 4 + r;
                    float v = which ? acc1[fi][fj][r] : acc0[fi][fj][r];
                    CS[row][c] = f2h(cok ? v + bb : 0.f);   // N-pad cols -> clean 0
                }
            }
        }
        __syncthreads();
        // 2048 chunks of 16B; consecutive threads -> consecutive bytes in a row
#pragma unroll
        for (int it = 0; it < 4; ++it) {
            int chunk = t + it * 512;
            int row = chunk >> 4;
            int co = (chunk & 15) * 8;
            int grr = row0 + row;
            if (grr < M) {
                f16x8 vv = *(f16x8*)&CS[row][co];
                *(f16x8*)&Cout[(size_t)grr * 256 + col0 + co] = vv;
            }
        }
        __syncthreads();
    }
}

// ---------------- fused edge phase: packed-fp16 single-pass softmax+aggregate ----------------
// r4 structure (1 node/wave, 2-deep gather pipeline) — at its measured plateau.

__global__ __launch_bounds__(256) void fused_edge_kernel(
    const int* __restrict__ rowptr, const int* __restrict__ ssrc,
    const u16* __restrict__ xl16, const u16* __restrict__ xr16,
    const u16* __restrict__ atth,
    u16* __restrict__ Oh, int dorelu)
{
    int i = blockIdx.x * 4 + (threadIdx.x >> 6);
    if (i >= NN) return;
    int lane = threadIdx.x & 63;
    int d0 = lane * 4;
    int lb = d0 * 2;                 // lane byte offset into fp16 row

    uint2 atr = *(const uint2*)&atth[d0];
    h2v at0h = *(h2v*)&atr.x, at1h = *(h2v*)&atr.y;
    const h2v c02 = {(_Float16)0.2f, (_Float16)0.2f};
    const char* xlb = (const char*)xl16;

    uint2 xrr = *(const uint2*)&xr16[(size_t)i * 256 + d0];
    h2v xr0h = *(h2v*)&xrr.x, xr1h = *(h2v*)&xrr.y;

    int beg = __builtin_amdgcn_readfirstlane(rowptr[i]);
    int end = __builtin_amdgcn_readfirstlane(rowptr[i + 1]);

    float m = -1e30f, ssum = 0.f;
    float4 acc = make_float4(0.f, 0.f, 0.f, 0.f);

    auto ldrow = [&](int o) -> uint2 {
        return *(const uint2*)(xlb + o + lb);
    };
    auto edge_score = [&](uint2 g) -> float {
        h2v x0 = *(h2v*)&g.x, x1 = *(h2v*)&g.y;
        h2v s = x0 + xr0h; s = hmax2v(s, s * c02);
        float e = __builtin_amdgcn_fdot2(s, at0h, 0.f, false);
        s = x1 + xr1h; s = hmax2v(s, s * c02);
        return __builtin_amdgcn_fdot2(s, at1h, e, false);
    };
    auto single_update = [&](uint2 g) {
        float e = f32_wave_sum63(edge_score(g));
        h2v x0 = *(h2v*)&g.x, x1 = *(h2v*)&g.y;
        float nm = fmaxf(m, e);
        float sc = __expf(m - nm);
        float w = __expf(e - nm);
        acc.x = fmaf(w, (float)x0.x, acc.x * sc);
        acc.y = fmaf(w, (float)x0.y, acc.y * sc);
        acc.z = fmaf(w, (float)x1.x, acc.z * sc);
        acc.w = fmaf(w, (float)x1.y, acc.w * sc);
        ssum = fmaf(ssum, sc, w);
        m = nm;
    };

    int p = beg;
    if (p + 3 < end) {
        // ---- prologue: block A gathers, block B gathers, block C offsets ----
        int o0 = __builtin_amdgcn_readfirstlane(ssrc[p]);
        int o1 = __builtin_amdgcn_readfirstlane(ssrc[p + 1]);
        int o2 = __builtin_amdgcn_readfirstlane(ssrc[p + 2]);
        int o3 = __builtin_amdgcn_readfirstlane(ssrc[p + 3]);
        uint2 a0 = ldrow(o0), a1 = ldrow(o1), a2 = ldrow(o2), a3 = ldrow(o3);

        bool hB = (p + 7 < end);
        uint2 b0, b1, b2, b3;
        if (hB) {
            int q0 = __builtin_amdgcn_readfirstlane(ssrc[p + 4]);
            int q1 = __builtin_amdgcn_readfirstlane(ssrc[p + 5]);
            int q2 = __builtin_amdgcn_readfirstlane(ssrc[p + 6]);
            int q3 = __builtin_amdgcn_readfirstlane(ssrc[p + 7]);
            b0 = ldrow(q0); b1 = ldrow(q1); b2 = ldrow(q2); b3 = ldrow(q3);
        }
        bool hC = (p + 11 < end);
        int co0 = 0, co1 = 0, co2 = 0, co3 = 0;
        if (hC) {
            co0 = __builtin_amdgcn_readfirstlane(ssrc[p + 8]);
            co1 = __builtin_amdgcn_readfirstlane(ssrc[p + 9]);
            co2 = __builtin_amdgcn_readfirstlane(ssrc[p + 10]);
            co3 = __builtin_amdgcn_readfirstlane(ssrc[p + 11]);
        }

        for (;;) {
            // issue block-C gathers (2 blocks ahead of compute)
            uint2 cg0, cg1, cg2, cg3;
            if (hC) {
                cg0 = ldrow(co0); cg1 = ldrow(co1); cg2 = ldrow(co2); cg3 = ldrow(co3);
            }
            // fetch block-D offsets
            bool hD = (p + 15 < end);
            int do0 = 0, do1 = 0, do2 = 0, do3 = 0;
            if (hD) {
                do0 = __builtin_amdgcn_readfirstlane(ssrc[p + 12]);
                do1 = __builtin_amdgcn_readfirstlane(ssrc[p + 13]);
                do2 = __builtin_amdgcn_readfirstlane(ssrc[p + 14]);
                do3 = __builtin_amdgcn_readfirstlane(ssrc[p + 15]);
            }

            // ---- compute block A ----
            h2v x00 = *(h2v*)&a0.x, x01 = *(h2v*)&a0.y;
            h2v x10 = *(h2v*)&a1.x, x11 = *(h2v*)&a1.y;
            h2v x20 = *(h2v*)&a2.x, x21 = *(h2v*)&a2.y;
            h2v x30 = *(h2v*)&a3.x, x31 = *(h2v*)&a3.y;

            h2v s;
            float e0, e1, e2, e3;
            s = x00 + xr0h; s = hmax2v(s, s * c02);
            e0 = __builtin_amdgcn_fdot2(s, at0h, 0.f, false);
            s = x01 + xr1h; s = hmax2v(s, s * c02);
            e0 = __builtin_amdgcn_fdot2(s, at1h, e0, false);
            s = x10 + xr0h; s = hmax2v(s, s * c02);
            e1 = __builtin_amdgcn_fdot2(s, at0h, 0.f, false);
            s = x11 + xr1h; s = hmax2v(s, s * c02);
            e1 = __builtin_amdgcn_fdot2(s, at1h, e1, false);
            s = x20 + xr0h; s = hmax2v(s, s * c02);
            e2 = __builtin_amdgcn_fdot2(s, at0h, 0.f, false);
            s = x21 + xr1h; s = hmax2v(s, s * c02);
            e2 = __builtin_amdgcn_fdot2(s, at1h, e2, false);
            s = x30 + xr0h; s = hmax2v(s, s * c02);
            e3 = __builtin_amdgcn_fdot2(s, at0h, 0.f, false);
            s = x31 + xr1h; s = hmax2v(s, s * c02);
            e3 = __builtin_amdgcn_fdot2(s, at1h, e3, false);

            // packed-pair DPP reduce: two independent VALU chains
            H2U u01, u23, r01, r23;
            u01.h.x = (_Float16)e0; u01.h.y = (_Float16)e1;
            u23.h.x = (_Float16)e2; u23.h.y = (_Float16)e3;
            r01.u = h2_wave_sum63(u01.h);
            r23.u = h2_wave_sum63(u23.h);
            float es0 = (float)r01.h.x, es1 = (float)r01.h.y;
            float es2 = (float)r23.h.x, es3 = (float)r23.h.y;

            float nm = fmaxf(fmaxf(m, es0), fmaxf(fmaxf(es1, es2), es3));
            float sc = __expf(m - nm);
            float w0 = __expf(es0 - nm);
            float w1 = __expf(es1 - nm);
            float w2 = __expf(es2 - nm);
            float w3 = __expf(es3 - nm);
            float ax0 = fmaf(w1, (float)x10.x, w0 * (float)x00.x);
            float ax1 = fmaf(w3, (float)x30.x, w2 * (float)x20.x);
            float ay0 = fmaf(w1, (float)x10.y, w0 * (float)x00.y);
            float ay1 = fmaf(w3, (float)x30.y, w2 * (float)x20.y);
            float az0 = fmaf(w1, (float)x11.x, w0 * (float)x01.x);
            float az1 = fmaf(w3, (float)x31.x, w2 * (float)x21.x);
            float aw0 = fmaf(w1, (float)x11.y, w0 * (float)x01.y);
            float aw1 = fmaf(w3, (float)x31.y, w2 * (float)x21.y);
            acc.x = fmaf(acc.x, sc, ax0 + ax1);
            acc.y = fmaf(acc.y, sc, ay0 + ay1);
            acc.z = fmaf(acc.z, sc, az0 + az1);
            acc.w = fmaf(acc.w, sc, aw0 + aw1);
            ssum = fmaf(ssum, sc, (w0 + w1) + (w2 + w3));
            m = nm;

            p += 4;
            if (!hB) break;
            // rotate pipeline: A <- B <- C; C-offsets <- D-offsets
            a0 = b0; a1 = b1; a2 = b2; a3 = b3;
            b0 = cg0; b1 = cg1; b2 = cg2; b3 = cg3;
            hB = hC; hC = hD;
            co0 = do0; co1 = do1; co2 = do2; co3 = do3;
        }
    }

    // remainder (0..3 edges): hoist gathers ahead of processing
    int rem = end - p;
    if (rem > 0) {
        int o0 = __builtin_amdgcn_readfirstlane(ssrc[p]);
        int o1 = 0, o2 = 0;
        if (rem > 1) o1 = __builtin_amdgcn_readfirstlane(ssrc[p + 1]);
        if (rem > 2) o2 = __builtin_amdgcn_readfirstlane(ssrc[p + 2]);
        uint2 g0 = ldrow(o0);
        uint2 g1, g2;
        if (rem > 1) g1 = ldrow(o1);
        if (rem > 2) g2 = ldrow(o2);
        single_update(g0);
        if (rem > 1) single_update(g1);
        if (rem > 2) single_update(g2);
    }

    float inv = 1.f / ssum;
    acc.x *= inv; acc.y *= inv; acc.z *= inv; acc.w *= inv;
    if (dorelu) {
        acc.x = fmaxf(acc.x, 0.f); acc.y = fmaxf(acc.y, 0.f);
        acc.z = fmaxf(acc.z, 0.f); acc.w = fmaxf(acc.w, 0.f);
    }
    size_t obase = (size_t)i * 256 + d0;
    ushort4 hv;
    hv.x = f2h(acc.x); hv.y = f2h(acc.y); hv.z = f2h(acc.z); hv.w = f2h(acc.w);
    *(ushort4*)&Oh[obase] = hv;   // pad lanes harmless; B k-pads are zero
}

// ---------------- query head: 4 queries per wave; 8 gathers in flight ----------------

__global__ __launch_bounds__(256) void query_kernel(
    const int* __restrict__ qry, const u16* __restrict__ Ptop,
    const u16* __restrict__ Pbot, const float* __restrict__ Wm2,
    const float* __restrict__ bm2, float* __restrict__ out)
{
    int q = (blockIdx.x * 4 + (threadIdx.x >> 6)) * 4;
    if (q >= NQ) return;
    int lane = threadIdx.x & 63;
    int a0 = __builtin_amdgcn_readfirstlane(qry[q * 2 + 0]);
    int b0 = __builtin_amdgcn_readfirstlane(qry[q * 2 + 1]);
    int a1 = __builtin_amdgcn_readfirstlane(qry[q * 2 + 2]);
    int b1 = __builtin_amdgcn_readfirstlane(qry[q * 2 + 3]);
    int a2 = __builtin_amdgcn_readfirstlane(qry[q * 2 + 4]);
    int b2 = __builtin_amdgcn_readfirstlane(qry[q * 2 + 5]);
    int a3 = __builtin_amdgcn_readfirstlane(qry[q * 2 + 6]);
    int b3 = __builtin_amdgcn_readfirstlane(qry[q * 2 + 7]);
    float4 w  = *(const float4*)&Wm2[lane * 4];
    float4 t0 = ld4h(&Ptop[(size_t)a0 * HD + lane * 4]);
    float4 v0 = ld4h(&Pbot[(size_t)b0 * HD + lane * 4]);
    float4 t1 = ld4h(&Ptop[(size_t)a1 * HD + lane * 4]);
    float4 v1 = ld4h(&Pbot[(size_t)b1 * HD + lane * 4]);
    float4 t2 = ld4h(&Ptop[(size_t)a2 * HD + lane * 4]);
    float4 v2 = ld4h(&Pbot[(size_t)b2 * HD + lane * 4]);
    float4 t3 = ld4h(&Ptop[(size_t)a3 * HD + lane * 4]);
    float4 v3 = ld4h(&Pbot[(size_t)b3 * HD + lane * 4]);
    float s0 = fmaxf(t0.x + v0.x, 0.f) * w.x + fmaxf(t0.y + v0.y, 0.f) * w.y
             + fmaxf(t0.z + v0.z, 0.f) * w.z + fmaxf(t0.w + v0.w, 0.f) * w.w;
    float s1 = fmaxf(t1.x + v1.x, 0.f) * w.x + fmaxf(t1.y + v1.y, 0.f) * w.y
             + fmaxf(t1.z + v1.z, 0.f) * w.z + fmaxf(t1.w + v1.w, 0.f) * w.w;
    float s2 = fmaxf(t2.x + v2.x, 0.f) * w.x + fmaxf(t2.y + v2.y, 0.f) * w.y
             + fmaxf(t2.z + v2.z, 0.f) * w.z + fmaxf(t2.w + v2.w, 0.f) * w.w;
    float s3 = fmaxf(t3.x + v3.x, 0.f) * w.x + fmaxf(t3.y + v3.y, 0.f) * w.y
             + fmaxf(t3.z + v3.z, 0.f) * w.z + fmaxf(t3.w + v3.w, 0.f) * w.w;
    s0 = f32_wave_sum63(s0);
    s1 = f32_wave_sum63(s1);
    s2 = f32_wave_sum63(s2);
    s3 = f32_wave_sum63(s3);
    if (lane == 0) {
        float bb = bm2[0];
        out[q]     = fmaxf(s0 + bb, 0.f);
        out[q + 1] = fmaxf(s1 + bb, 0.f);
        out[q + 2] = fmaxf(s2 + bb, 0.f);
        out[q + 3] = fmaxf(s3 + bb, 0.f);
    }
}

// ---------------- launch ----------------

extern "C" void kernel_launch(void* const* d_in, const int* in_sizes, int n_in,
                              void* d_out, int out_size, void* d_ws, size_t ws_size,
                              hipStream_t stream) {
    const float* x    = (const float*)d_in[0];
    const int*   ei   = (const int*)d_in[1];
    const int*   qry  = (const int*)d_in[2];
    const float* W1l  = (const float*)d_in[3];
    const float* b1l  = (const float*)d_in[4];
    const float* W1r  = (const float*)d_in[5];
    const float* b1r  = (const float*)d_in[6];
    const float* att1 = (const float*)d_in[7];
    const float* W2l  = (const float*)d_in[8];
    const float* b2l  = (const float*)d_in[9];
    const float* W2r  = (const float*)d_in[10];
    const float* b2r  = (const float*)d_in[11];
    const float* att2 = (const float*)d_in[12];
    const float* Wm1  = (const float*)d_in[13];
    const float* bm1  = (const float*)d_in[14];
    const float* Wm2  = (const float*)d_in[15];
    const float* bm2  = (const float*)d_in[16];
    float* out = (float*)d_out;

    // workspace carve-up (all node tensors fp16 stride-256)
    u16* xl16    = (u16*)d_ws;                   // NN*256 halfs (25.6 MB)
    u16* xr16    = xl16 + (size_t)NN * 256;      // NN*256 halfs (25.6 MB)
    int* rowptr  = (int*)(xr16 + (size_t)NN * 256);  // NN+1
    int* fill    = rowptr + NN + 1;              // NN (count buffer)
    int* ssrc    = fill + NN;                    // ET
    int* bsum    = ssrc + ET;                    // 256
    u16* atth1   = (u16*)(bsum + 256);           // 256 halfs
    u16* atth2   = atth1 + 256;                  // 256 halfs
    uintptr_t wp = (uintptr_t)(atth2 + 256);
    wp = (wp + 63) & ~(uintptr_t)63;
    u16* W1lT = (u16*)wp;                        // 256*128 each
    u16* W1rT = W1lT + 256 * 128;
    u16* W2lT = W1rT + 256 * 128;                // 256*256 each from here
    u16* W2rT = W2lT + 65536;
    u16* WmtT = W2rT + 65536;
    u16* WmbT = WmtT + 65536;
    u16* Asp  = WmbT + 65536;                    // NN*256 fp16
    u16* Ptop16 = xl16;                          // head overlays (dead after layer-2)
    u16* Pbot16 = xr16;

    dim3 blk(256);
    int gET = (ET + 255) / 256;
    int gNode = (NN + 3) / 4;                    // 4 waves/block, 1 node/wave
    int nb = (NN + 255) / 256;                   // 196 scan blocks
    dim3 gg((NN + 127) / 128, 2);                // 782 gemm blocks (128x128 tiles)

    // ---- zero degree counters (graph-capture-safe), then conversions + count ----
    hipMemsetAsync(fill, 0, (size_t)NN * sizeof(int), stream);
    conv_all<<<CONVX_BLOCKS + 1282 + gET, blk, 0, stream>>>(x, ei, Asp,
        W1l, W1r, W2l, W2r, Wm1, att1, att2,
        W1lT, W1rT, W2lT, W2rT, WmtT, WmbT, atth1, atth2, fill);

    // ---- CSR build (2-dispatch scan) ----
    scan1_kernel<<<nb, blk, 0, stream>>>(fill, rowptr, bsum);   // also zeroes fill
    scan3_kernel<<<nb, blk, 0, stream>>>(rowptr, bsum, nb);     // internal bsum scan
    scatter_kernel<<<gET, blk, 0, stream>>>(ei, rowptr, fill, ssrc);

    // ---- layer 1 (A = x fp16, Kp=128): both outputs fp16 stride-256 ----
    gemm_pair<<<gg, dim3(512), 0, stream>>>(Asp, 128, W1lT, W1rT,
                                      b1l, b1r, (void*)xl16, (void*)xr16, NN, DD, 3);
    fused_edge_kernel<<<gNode, blk, 0, stream>>>(rowptr, ssrc, xl16, xr16, atth1, Asp, 1);

    // ---- layer 2 (A = h fp16, Kp=256) ----
    gemm_pair<<<gg, dim3(512), 0, stream>>>(Asp, 256, W2lT, W2rT,
                                      b2l, b2r, (void*)xl16, (void*)xr16, NN, DD, 3);
    fused_edge_kernel<<<gNode, blk, 0, stream>>>(rowptr, ssrc, xl16, xr16, atth2, Asp, 0);

    // ---- head precompute (A = emb fp16, Kp=256): both outputs fp16 ----
    gemm_pair<<<gg, dim3(512), 0, stream>>>(Asp, 256, WmtT, WmbT,
                                      bm1, (const float*)nullptr, (void*)Ptop16, (void*)Pbot16, NN, HD, 3);

    // ---- per-query head ----
    query_kernel<<<(NQ / 4 + 3) / 4, blk, 0, stream>>>(qry, Ptop16, Pbot16, Wm2, bm2, out);
}